// Round 6
// baseline (1307.149 us; speedup 1.0000x reference)
//
#include <hip/hip_runtime.h>
#include <hip/hip_bf16.h>

// GraphSAGE 4-layer forward.
// R2: bf16 activations; aggregate-then-GEMM; fused MFMA GEMM + partial stats.
// R3: k_agg MLP restructure (16-lane groups x dwordx4, 8 edges/iter).
// R4: BN folded into next layer (sc -> B-tile scale, sh -> effective bias).
// R5: binned CSR build (LDS counting sort, coalesced writes); per-graph pooling.
// R6/R7: LDS-free GEMM experiments -- learned: ~72-76us wall is schedule- and
//     occupancy-invariant (~700 GB/s effective, ~11 lines/CU in flight).
// R8: FUSE aggregation into the GEMM (k_layer): each block gathers its own
//     128 rows into the LDS A-tile. Kills the 51MB/layer aggb round-trip,
//     4 launches, and overlaps gather latency with MFMA of sibling blocks.

#define EPS_BN 1e-5f
#define BSH 9                 // 512 nodes per bucket
#define BCHUNK 4096           // edges per k_bin block
#define PCAP 10240            // max edges per bucket for LDS staging (mean 8192)

typedef __attribute__((ext_vector_type(8))) short bf16x8;
typedef __attribute__((ext_vector_type(4))) float f32x4;

// ---------------- embedding gather -> bf16 h ---------------------------------
__global__ __launch_bounds__(256) void k_embed(const int* __restrict__ feat,
                                               const float* __restrict__ emb,
                                               __hip_bfloat162* __restrict__ hb2, int n) {
  int idx = blockIdx.x * 256 + threadIdx.x;   // one bf16x2 each
  if (idx < n * 64) {
    int i = idx >> 6, c2 = idx & 63;
    float2 v = ((const float2*)emb)[feat[i] * 64 + c2];
    hb2[idx] = __float22bfloat162_rn(v);
  }
}

// ---------------- W -> bf16, transposed: Wt[l][n][k] = W[l][k][n] ------------
__global__ __launch_bounds__(256) void k_wconv(const float* __restrict__ W,
                                               __hip_bfloat16* __restrict__ Wt, int total) {
  int idx = blockIdx.x * 256 + threadIdx.x;
  if (idx < total) {
    int l = idx >> 14, r = idx & 16383, nn = r >> 7, kk = r & 127;
    Wt[idx] = __float2bfloat16(W[(l << 14) + kk * 128 + nn]);
  }
}

// ---------------- per-graph node offsets via binary search (gid sorted) ------
__global__ void k_gcount(const int* __restrict__ gid, int* __restrict__ gcnt,
                         int* __restrict__ gstart, int n, int G) {
  int g = blockIdx.x * blockDim.x + threadIdx.x;
  if (g >= G) return;
  int lo0 = 0, hi = n;
  while (lo0 < hi) { int mid = (lo0 + hi) >> 1; if (gid[mid] < g) lo0 = mid + 1; else hi = mid; }
  int lo1 = lo0; hi = n;
  while (lo1 < hi) { int mid = (lo1 + hi) >> 1; if (gid[mid] < g + 1) lo1 = mid + 1; else hi = mid; }
  gstart[g] = lo0;
  gcnt[g] = lo1 - lo0;
}

// ---------------- bucket histogram over dst (LDS-staged) ---------------------
__global__ __launch_bounds__(256) void k_bhist(const int* __restrict__ dst,
                                               int* __restrict__ bktcnt, int m, int nbkt) {
  __shared__ int h[256];
  int t = threadIdx.x;
  h[t] = 0;
  __syncthreads();
#pragma unroll
  for (int k = 0; k < 4; ++k) {
    int idx = blockIdx.x * BCHUNK + k * 1024 + t * 4;
    if (idx + 4 <= m) {
      int4 d = *(const int4*)&dst[idx];
      atomicAdd(&h[d.x >> BSH], 1);
      atomicAdd(&h[d.y >> BSH], 1);
      atomicAdd(&h[d.z >> BSH], 1);
      atomicAdd(&h[d.w >> BSH], 1);
    } else {
      for (int e = idx; e < m && e < idx + 4; ++e) atomicAdd(&h[dst[e] >> BSH], 1);
    }
  }
  __syncthreads();
  for (int b = t; b < nbkt; b += 256)
    if (h[b]) atomicAdd(&bktcnt[b], h[b]);
}

// ---------------- scan bucket counts -> base & cursor ------------------------
__global__ void k_bscan(const int* __restrict__ bktcnt, int* __restrict__ bbase,
                        int* __restrict__ bcur, int m, int nbkt) {
  __shared__ int sh[256];
  int t = threadIdx.x;
  int v = (t < nbkt) ? bktcnt[t] : 0;
  sh[t] = v;
  __syncthreads();
  for (int o = 1; o < 256; o <<= 1) {
    int x = (t >= o) ? sh[t - o] : 0;
    __syncthreads();
    sh[t] += x;
    __syncthreads();
  }
  if (t < nbkt) { bbase[t] = sh[t] - v; bcur[t] = sh[t] - v; }
  if (t == 0) bbase[nbkt] = m;
}

// ---------------- bin edges by bucket (LDS counting sort, coalesced out) -----
__global__ __launch_bounds__(256) void k_bin(const int* __restrict__ src, const int* __restrict__ dst,
                                             int* __restrict__ bcur, uint2* __restrict__ binned,
                                             int m, int nbkt) {
  __shared__ uint2 st[BCHUNK];
  __shared__ int bcnt[256], boff[256], bres[256], wcur[256], ss[256];
  int t = threadIdx.x;
  int e0 = blockIdx.x * BCHUNK;
  int cn = min(BCHUNK, m - e0);
  int sv[16], dv[16];
  for (int b = t; b < 256; b += 256) bcnt[b] = 0;
  __syncthreads();
#pragma unroll
  for (int k = 0; k < 16; ++k) {
    int idx = e0 + k * 256 + t;
    if (idx < e0 + cn) {
      sv[k] = src[idx];
      dv[k] = dst[idx];
      atomicAdd(&bcnt[dv[k] >> BSH], 1);
    } else dv[k] = -1;
  }
  __syncthreads();
  int v = (t < nbkt) ? bcnt[t] : 0;
  ss[t] = v;
  __syncthreads();
  for (int o = 1; o < 256; o <<= 1) {
    int x = (t >= o) ? ss[t - o] : 0;
    __syncthreads();
    ss[t] += x;
    __syncthreads();
  }
  if (t < nbkt) {
    int ex = ss[t] - v;
    boff[t] = ex;
    wcur[t] = ex;
    if (v) bres[t] = atomicAdd(&bcur[t], v);
  }
  __syncthreads();
#pragma unroll
  for (int k = 0; k < 16; ++k) {
    if (dv[k] >= 0) {
      int b = dv[k] >> BSH;
      int p = atomicAdd(&wcur[b], 1);
      st[p] = make_uint2((unsigned)sv[k], (unsigned)dv[k]);
    }
  }
  __syncthreads();
  for (int j = t; j < cn; j += 256) {
    uint2 e = st[j];
    int b = (int)(e.y >> BSH);
    binned[(size_t)bres[b] + (j - boff[b])] = e;
  }
}

// ---------------- per-bucket node counts (LDS, coalesced cnt write) ----------
__global__ __launch_bounds__(256) void k_cnt(const uint2* __restrict__ binned,
                                             const int* __restrict__ bbase,
                                             int* __restrict__ cnt, int n) {
  __shared__ int h[512];
  int b = blockIdx.x, t = threadIdx.x;
  int base = b << BSH;
  int nn = min(512, n - base);
  h[t] = 0; h[t + 256] = 0;
  __syncthreads();
  int lo = bbase[b], hi = bbase[b + 1];
  for (int j = lo + t; j < hi; j += 256) atomicAdd(&h[(int)binned[j].y - base], 1);
  __syncthreads();
  if (t < nn) cnt[base + t] = h[t];
  if (t + 256 < nn) cnt[base + t + 256] = h[t + 256];
}

// ---------------- exclusive scan of cnt -> row_ptr (3 kernels) ---------------
__global__ __launch_bounds__(256) void k_scan1(const int* __restrict__ cnt,
                                               int* __restrict__ excl,
                                               int* __restrict__ blk_sums, int n) {
  __shared__ int sh[256];
  int t = threadIdx.x;
  int base = blockIdx.x * 1024 + t * 4;
  int4 v = {0, 0, 0, 0};
  if (base < n) v = *(const int4*)&cnt[base];
  int s = v.x + v.y + v.z + v.w;
  sh[t] = s;
  __syncthreads();
  for (int off = 1; off < 256; off <<= 1) {
    int x = (t >= off) ? sh[t - off] : 0;
    __syncthreads();
    sh[t] += x;
    __syncthreads();
  }
  int ex = sh[t] - s;
  if (t == 255) blk_sums[blockIdx.x] = sh[255];
  if (base < n) {
    excl[base]     = ex;
    excl[base + 1] = ex + v.x;
    excl[base + 2] = ex + v.x + v.y;
    excl[base + 3] = ex + v.x + v.y + v.z;
  }
}

__global__ void k_scan2(int* __restrict__ bs, int nb) {
  __shared__ int sh[128];
  int t = threadIdx.x;
  int v = (t < nb) ? bs[t] : 0;
  sh[t] = v;
  __syncthreads();
  for (int off = 1; off < 128; off <<= 1) {
    int x = (t >= off) ? sh[t - off] : 0;
    __syncthreads();
    sh[t] += x;
    __syncthreads();
  }
  if (t < nb) bs[t] = sh[t] - v;
}

__global__ __launch_bounds__(256) void k_scan3(int* __restrict__ rp, const int* __restrict__ bs,
                                               const int* __restrict__ cnt, int* __restrict__ cursor,
                                               float* __restrict__ deg, int n, int ne) {
  int i = blockIdx.x * 256 + threadIdx.x;
  if (i < n) {
    int r = rp[i] + bs[i >> 10];
    rp[i] = r;
    cursor[i] = r;
    int c = cnt[i];
    deg[i] = (float)(c > 0 ? c : 1);
  }
  if (i == 0) rp[n] = ne;
}

// ---------------- place edges into CSR (per-bucket LDS sort, coalesced) ------
__global__ __launch_bounds__(256) void k_place(const uint2* __restrict__ binned,
                                               const int* __restrict__ bbase,
                                               const int* __restrict__ rp,
                                               int* __restrict__ cursor,
                                               int* __restrict__ csr_src, int n) {
  int b = blockIdx.x, t = threadIdx.x;
  int base = b << BSH;
  int lo = bbase[b], hi = bbase[b + 1], m = hi - lo;
  if (m <= 0) return;
  if (m > PCAP) {                          // fallback: global-atomic scatter
    for (int j = lo + t; j < hi; j += 256) {
      uint2 e = binned[j];
      int p = atomicAdd(&cursor[(int)e.y], 1);
      csr_src[p] = (int)e.x;
    }
    return;
  }
  __shared__ int h[512], loff[512], wc[512], ss[256];
  __shared__ int stage[PCAP];
  h[t] = 0; h[t + 256] = 0;
  __syncthreads();
  for (int j = lo + t; j < hi; j += 256) atomicAdd(&h[(int)binned[j].y - base], 1);
  __syncthreads();
  int a0 = h[2 * t], a1 = h[2 * t + 1];
  int s = a0 + a1;
  ss[t] = s;
  __syncthreads();
  for (int o = 1; o < 256; o <<= 1) {
    int x = (t >= o) ? ss[t - o] : 0;
    __syncthreads();
    ss[t] += x;
    __syncthreads();
  }
  int ex = ss[t] - s;
  loff[2 * t] = ex; loff[2 * t + 1] = ex + a0;
  wc[2 * t] = ex;   wc[2 * t + 1] = ex + a0;
  __syncthreads();
  for (int j = lo + t; j < hi; j += 256) {
    uint2 e = binned[j];
    int p = atomicAdd(&wc[(int)e.y - base], 1);
    stage[p] = (int)e.x;
  }
  __syncthreads();
  int cb = rp[base];
  for (int j = t; j < m; j += 256) csr_src[cb + j] = stage[j];
}

// ---------------- init: identity BN affine + layer-0 effective bias ----------
__global__ void k_prep(const float* __restrict__ b0, float* __restrict__ ss0,
                       float* __restrict__ beff0) {
  int t = threadIdx.x;
  ss0[t] = 1.f;
  ss0[128 + t] = 0.f;
  beff0[t] = b0[t];
}

// ---------------- pre-scale this layer's Wt by sc[k] -> Wst2/Wnt2 ------------
__global__ __launch_bounds__(256) void k_wscale(const __hip_bfloat16* __restrict__ Wst,
                                                const __hip_bfloat16* __restrict__ Wnt,
                                                const float* __restrict__ ssl,
                                                __hip_bfloat16* __restrict__ Wst2,
                                                __hip_bfloat16* __restrict__ Wnt2) {
  int id = blockIdx.x * 256 + threadIdx.x;     // 0..4095
  int half = id >> 11;                          // 0: Ws, 1: Wn
  int ch = id & 2047;                           // uint4 chunk within 16384 el
  const uint4* Wsrc = (const uint4*)(half ? Wnt : Wst);
  uint4* Wdst = (uint4*)(half ? Wnt2 : Wst2);
  uint4 v = Wsrc[ch];
  int k0 = (ch * 8) & 127;
  __hip_bfloat162* pv = (__hip_bfloat162*)&v;
#pragma unroll
  for (int j = 0; j < 4; ++j) {
    float2 f = __bfloat1622float2(pv[j]);
    f.x *= ssl[k0 + 2 * j]; f.y *= ssl[k0 + 2 * j + 1];
    pv[j] = __float22bfloat162_rn(f);
  }
  Wdst[ch] = v;
}

// ---------------- fused layer: gather+agg -> LDS, self -> LDS, MFMA, stats ---
// Block owns 128 rows. Phase 1: stage self rows into Ah (padded LDS).
// Phase 2: each wave mean-aggregates its 32 owned rows into Aa (4x16-lane
// groups, 8 edges in flight). Phase 3: MFMA from LDS A, global B (prescaled,
// L2-hot). Epilogue: beff + PReLU + bf16 store + per-block stats.
__device__ __forceinline__ void acc8(float* a, uint4 v) {
  float2 f;
  f = __bfloat1622float2(*(const __hip_bfloat162*)&v.x); a[0] += f.x; a[1] += f.y;
  f = __bfloat1622float2(*(const __hip_bfloat162*)&v.y); a[2] += f.x; a[3] += f.y;
  f = __bfloat1622float2(*(const __hip_bfloat162*)&v.z); a[4] += f.x; a[5] += f.y;
  f = __bfloat1622float2(*(const __hip_bfloat162*)&v.w); a[6] += f.x; a[7] += f.y;
}

__global__ __launch_bounds__(256) void k_layer(
    const __hip_bfloat16* __restrict__ hb,      // prev raw rst [N][128] bf16
    const int* __restrict__ rp, const int* __restrict__ csr_src,
    const float* __restrict__ deg,
    const float* __restrict__ ssl,              // prev-layer [sc|sh]
    const __hip_bfloat16* __restrict__ Wst2, const __hip_bfloat16* __restrict__ Wnt2,
    const float* __restrict__ beff, const float* __restrict__ pw,
    __hip_bfloat16* __restrict__ hbn, float* __restrict__ partial, int n) {
  __shared__ short Ah[128 * 136];
  __shared__ short Aa[128 * 136];
  __shared__ float ls[128], lq[128];
  const uint4* hb4 = (const uint4*)hb;
  int t = threadIdx.x;
  int row0 = blockIdx.x * 128;
  if (t < 128) { ls[t] = 0.f; lq[t] = 0.f; }

  // ---- phase 1: stage self tile (raw rst rows) ----
  for (int ch = t; ch < 2048; ch += 256) {
    int r = ch >> 4, c8 = (ch & 15) * 8;
    uint4 va = make_uint4(0, 0, 0, 0);
    if (row0 + r < n) va = *(const uint4*)(hb + (size_t)(row0 + r) * 128 + c8);
    *(uint4*)&Ah[r * 136 + c8] = va;
  }

  // ---- phase 2: gather/aggregate this wave's 32 rows into Aa ----
  int lane = t & 63, w = t >> 6;
  int g = lane >> 4, lr = lane & 15;
  for (int r32 = 0; r32 < 32; ++r32) {
    int i = row0 + w * 32 + r32;
    if (i >= n) break;
    int beg = rp[i], end = rp[i + 1];
    float a[8];
#pragma unroll
    for (int c = 0; c < 8; ++c) a[c] = 0.f;
    int e = beg;
    for (; e + 8 <= end; e += 8) {        // 8 edges per wave-iteration
      int s0 = csr_src[e + g];
      int s1 = csr_src[e + 4 + g];
      uint4 v0 = hb4[(size_t)s0 * 16 + lr];
      uint4 v1 = hb4[(size_t)s1 * 16 + lr];
      acc8(a, v0);
      acc8(a, v1);
    }
    for (; e + g < end; e += 4) {         // predicated 4-edge tail
      int s = csr_src[e + g];
      uint4 v = hb4[(size_t)s * 16 + lr];
      acc8(a, v);
    }
#pragma unroll
    for (int c = 0; c < 8; ++c) {         // combine the 4 groups
      a[c] += __shfl_xor(a[c], 16, 64);
      a[c] += __shfl_xor(a[c], 32, 64);
    }
    if (g == 0) {
      float v[8];
      if (beg == end) {                   // zero-degree: cancel folded affine
#pragma unroll
        for (int c = 0; c < 8; ++c) {
          float sc = ssl[lr * 8 + c], sh = ssl[128 + lr * 8 + c];
          v[c] = (sc != 0.f) ? (-sh / sc) : 0.f;
        }
      } else {
        float invd = 1.0f / deg[i];
#pragma unroll
        for (int c = 0; c < 8; ++c) v[c] = a[c] * invd;
      }
      __hip_bfloat162 p0 = __float22bfloat162_rn(make_float2(v[0], v[1]));
      __hip_bfloat162 p1 = __float22bfloat162_rn(make_float2(v[2], v[3]));
      __hip_bfloat162 p2 = __float22bfloat162_rn(make_float2(v[4], v[5]));
      __hip_bfloat162 p3 = __float22bfloat162_rn(make_float2(v[6], v[7]));
      uint4 o;
      o.x = *(unsigned int*)&p0; o.y = *(unsigned int*)&p1;
      o.z = *(unsigned int*)&p2; o.w = *(unsigned int*)&p3;
      *(uint4*)&Aa[(w * 32 + r32) * 136 + lr * 8] = o;
    }
  }
  __syncthreads();

  // ---- phase 3: MFMA from LDS A, global B ----
  int lr16 = lane & 15, lk8 = (lane >> 4) * 8;
  f32x4 acc[2][8];
#pragma unroll
  for (int fm = 0; fm < 2; ++fm)
#pragma unroll
    for (int fn = 0; fn < 8; ++fn) acc[fm][fn] = (f32x4){0.f, 0.f, 0.f, 0.f};

  const short* As[2] = {Ah, Aa};
  const __hip_bfloat16* Bt[2] = {Wst2, Wnt2};
#pragma unroll
  for (int s = 0; s < 2; ++s) {
    const short* A = As[s];
    const __hip_bfloat16* B = Bt[s];
#pragma unroll
    for (int ks = 0; ks < 4; ++ks) {
      bf16x8 af[2], bfr[8];
#pragma unroll
      for (int fm = 0; fm < 2; ++fm)
        af[fm] = *(const bf16x8*)&A[(w * 32 + fm * 16 + lr16) * 136 + ks * 32 + lk8];
#pragma unroll
      for (int fn = 0; fn < 8; ++fn)
        bfr[fn] = *(const bf16x8*)(B + (size_t)(fn * 16 + lr16) * 128 + ks * 32 + lk8);
#pragma unroll
      for (int fm = 0; fm < 2; ++fm)
#pragma unroll
        for (int fn = 0; fn < 8; ++fn)
          acc[fm][fn] = __builtin_amdgcn_mfma_f32_16x16x32_bf16(af[fm], bfr[fn], acc[fm][fn], 0, 0, 0);
    }
  }

  // ---- epilogue: beff + PReLU + bf16 store + stats ----
  int rb = (lane >> 4) * 4;    // C/D: col = lane&15, row = 4*(lane>>4)+reg  [m89]
  float sacc[8], qacc[8];
#pragma unroll
  for (int fn = 0; fn < 8; ++fn) { sacc[fn] = 0.f; qacc[fn] = 0.f; }
#pragma unroll
  for (int fm = 0; fm < 2; ++fm) {
    int rbase = row0 + w * 32 + fm * 16 + rb;
#pragma unroll
    for (int fn = 0; fn < 8; ++fn) {
      int col = fn * 16 + lr16;
      float bb = beff[col], pp = pw[col];
#pragma unroll
      for (int r = 0; r < 4; ++r) {
        int grow = rbase + r;
        if (grow < n) {
          float v = acc[fm][fn][r] + bb;
          v = v > 0.f ? v : pp * v;
          hbn[(size_t)grow * 128 + col] = __float2bfloat16(v);
          sacc[fn] += v; qacc[fn] += v * v;
        }
      }
    }
  }
#pragma unroll
  for (int fn = 0; fn < 8; ++fn) {
    int col = fn * 16 + lr16;
    atomicAdd(&ls[col], sacc[fn]);
    atomicAdd(&lq[col], qacc[fn]);
  }
  __syncthreads();
  if (t < 128) {
    partial[(size_t)blockIdx.x * 256 + t]       = ls[t];
    partial[(size_t)blockIdx.x * 256 + 128 + t] = lq[t];
  }
}

// ------------- reduce partial stats -> BN affine + next-layer eff. bias ------
// beff uses ORIGINAL fp32 weights [k][n] layout -> coalesced loads.
__global__ __launch_bounds__(1024) void k_bnfin(const float* __restrict__ partial, int nb,
                                                const float* __restrict__ gamma,
                                                const float* __restrict__ beta,
                                                float* __restrict__ ss,
                                                const float* __restrict__ bias_next,
                                                const float* __restrict__ Ws_next,
                                                const float* __restrict__ Wn_next,
                                                float* __restrict__ beff_next,
                                                int has_next, int n) {
  __shared__ float red[4][256];
  __shared__ float shv[128];
  __shared__ float bred[8][128];
  int t = threadIdx.x, c = t & 255, part = t >> 8;
  float s = 0.f;
  for (int b = part; b < nb; b += 4) s += partial[(size_t)b * 256 + c];
  red[part][c] = s;
  __syncthreads();
  if (part == 0) red[0][c] = red[0][c] + red[1][c] + red[2][c] + red[3][c];
  __syncthreads();
  if (t < 128) {
    float inv_n = 1.0f / (float)n;
    float mu = red[0][t] * inv_n;
    float var = red[0][128 + t] * inv_n - mu * mu;
    float sc = rsqrtf(var + EPS_BN) * gamma[t];
    float sh = beta[t] - mu * sc;
    ss[t] = sc;
    ss[128 + t] = sh;
    shv[t] = sh;
  }
  __syncthreads();
  if (has_next) {
    int cc = t & 127, kg = t >> 7;       // 8 k-groups x 128 channels
    float acc = 0.f;
#pragma unroll
    for (int k = kg * 16; k < kg * 16 + 16; ++k)
      acc += shv[k] * (Ws_next[k * 128 + cc] + Wn_next[k * 128 + cc]);
    bred[kg][cc] = acc;
    __syncthreads();
    if (t < 128) {
      float r = bias_next[t];
#pragma unroll
      for (int kg2 = 0; kg2 < 8; ++kg2) r += bred[kg2][t];
      beff_next[t] = r;
    }
  }
}

// ------------- per-graph pool of raw rst (bf16): one block per graph ---------
__global__ __launch_bounds__(256) void k_pool(const uint4* __restrict__ hb4,
                                              const int* __restrict__ gstart,
                                              const int* __restrict__ gcnt,
                                              float* __restrict__ out, int l) {
  __shared__ float red[4][128];
  int g = blockIdx.x;
  int i0 = gstart[g], cg = gcnt[g];
  int t = threadIdx.x, w = t >> 6, lane = t & 63;
  int gi = lane >> 4, lr = lane & 15;
  float a[8];
#pragma unroll
  for (int c = 0; c < 8; ++c) a[c] = 0.f;
#pragma unroll 2
  for (int r = w * 4 + gi; r < cg; r += 16) {    // 16 rows in flight per block
    uint4 v = hb4[(size_t)(i0 + r) * 16 + lr];
    acc8(a, v);
  }
#pragma unroll
  for (int c = 0; c < 8; ++c) {                  // combine 4 groups in wave
    a[c] += __shfl_xor(a[c], 16, 64);
    a[c] += __shfl_xor(a[c], 32, 64);
  }
  if (gi == 0) {
#pragma unroll
    for (int c = 0; c < 8; ++c) red[w][lr * 8 + c] = a[c];
  }
  __syncthreads();
  if (t < 128)
    out[(size_t)g * 512 + l * 128 + t] = red[0][t] + red[1][t] + red[2][t] + red[3][t];
}

// ------------- finalize: mean + BN affine per layer section ------------------
__global__ __launch_bounds__(256) void k_div(float* __restrict__ out, const int* __restrict__ gcnt,
                                             const float* __restrict__ ssbuf, int m) {
  int i = blockIdx.x * 256 + threadIdx.x;
  if (i < m) {
    int g = i >> 9;
    int lc = i & 511;
    int l = lc >> 7, c = lc & 127;
    const float* ss = ssbuf + (l + 1) * 256;
    int cn = gcnt[g];
    out[i] = (cn > 0) ? (out[i] / (float)cn) * ss[c] + ss[128 + c] : 0.f;
  }
}

extern "C" void kernel_launch(void* const* d_in, const int* in_sizes, int n_in,
                              void* d_out, int out_size, void* d_ws, size_t ws_size,
                              hipStream_t stream) {
  const int*   in_feat = (const int*)d_in[0];
  const int*   src     = (const int*)d_in[1];
  const int*   dst     = (const int*)d_in[2];
  const int*   gid     = (const int*)d_in[3];
  const float* emb     = (const float*)d_in[4];
  const float* Wself   = (const float*)d_in[5];
  const float* Wneigh  = (const float*)d_in[6];
  const float* bvec    = (const float*)d_in[7];
  const float* gamma   = (const float*)d_in[8];
  const float* beta    = (const float*)d_in[9];
  const float* prelu   = (const float*)d_in[10];
  const int N = in_sizes[0];
  const int E = in_sizes[1];
  const int G = out_size / 512;
  float* out = (float*)d_out;
  const int NB = (N + 127) / 128;          // layer blocks
  const int NBKT = (N + 511) >> BSH;       // buckets (<=256 for N<=128K)

  char* p = (char*)d_ws;
  size_t off = 0;
  auto take = [&](size_t bytes) { void* r = p + off; off += (bytes + 255) & ~(size_t)255; return r; };
  __hip_bfloat16* hb0   = (__hip_bfloat16*)take((size_t)N * 128 * 2);
  __hip_bfloat16* hb1   = (__hip_bfloat16*)take((size_t)N * 128 * 2);
  __hip_bfloat16* Wst   = (__hip_bfloat16*)take((size_t)4 * 128 * 128 * 2);
  __hip_bfloat16* Wnt   = (__hip_bfloat16*)take((size_t)4 * 128 * 128 * 2);
  __hip_bfloat16* Wst2  = (__hip_bfloat16*)take((size_t)128 * 128 * 2);
  __hip_bfloat16* Wnt2  = (__hip_bfloat16*)take((size_t)128 * 128 * 2);
  float* partial        = (float*)take((size_t)NB * 256 * 4);
  float* ssbuf          = (float*)take((size_t)5 * 256 * 4);  // [l][sc|sh], l=0 identity
  float* beff           = (float*)take((size_t)4 * 128 * 4);
  uint2* binned  = (uint2*)take((size_t)E * 8);
  int*   csr_src = (int*)take((size_t)E * 4);
  int*   cnt     = (int*)take((size_t)N * 4);
  int*   rp      = (int*)take((size_t)(N + 1) * 4);
  int*   cursor  = (int*)take((size_t)N * 4);
  float* deg     = (float*)take((size_t)N * 4);
  int*   bs      = (int*)take(512);
  int*   gcnt    = (int*)take((size_t)G * 4);
  int*   gstart  = (int*)take((size_t)G * 4);
  int*   bktcnt  = (int*)take((size_t)NBKT * 4);
  int*   bbase   = (int*)take((size_t)(NBKT + 1) * 4);
  int*   bcur    = (int*)take((size_t)NBKT * 4);
  if (off > ws_size) return;

  hipMemsetAsync(bktcnt, 0, (size_t)NBKT * 4, stream);

  k_embed<<<(N * 64 + 255) / 256, 256, 0, stream>>>(in_feat, emb, (__hip_bfloat162*)hb0, N);
  k_wconv<<<(4 * 128 * 128 + 255) / 256, 256, 0, stream>>>(Wself, Wst, 4 * 128 * 128);
  k_wconv<<<(4 * 128 * 128 + 255) / 256, 256, 0, stream>>>(Wneigh, Wnt, 4 * 128 * 128);
  k_gcount<<<1, 128, 0, stream>>>(gid, gcnt, gstart, N, G);

  int nbb = (E + BCHUNK - 1) / BCHUNK;
  k_bhist<<<nbb, 256, 0, stream>>>(dst, bktcnt, E, NBKT);
  k_bscan<<<1, 256, 0, stream>>>(bktcnt, bbase, bcur, E, NBKT);
  k_bin<<<nbb, 256, 0, stream>>>(src, dst, bcur, binned, E, NBKT);
  k_cnt<<<NBKT, 256, 0, stream>>>(binned, bbase, cnt, N);
  int nsb = (N + 1023) / 1024;
  k_scan1<<<nsb, 256, 0, stream>>>(cnt, rp, bs, N);
  k_scan2<<<1, 128, 0, stream>>>(bs, nsb);
  k_scan3<<<(N + 255) / 256, 256, 0, stream>>>(rp, bs, cnt, cursor, deg, N, E);
  k_place<<<NBKT, 256, 0, stream>>>(binned, bbase, rp, cursor, csr_src, N);
  k_prep<<<1, 128, 0, stream>>>(bvec, ssbuf, beff);

  __hip_bfloat16* bufs[2] = {hb0, hb1};
  for (int l = 0; l < 4; ++l) {
    __hip_bfloat16* hin  = bufs[l & 1];
    __hip_bfloat16* hout = bufs[(l + 1) & 1];
    k_wscale<<<16, 256, 0, stream>>>(Wst + l * 16384, Wnt + l * 16384,
                                     ssbuf + l * 256, Wst2, Wnt2);
    k_layer<<<NB, 256, 0, stream>>>(hin, rp, csr_src, deg, ssbuf + l * 256,
                                    Wst2, Wnt2, beff + l * 128, prelu + l * 128,
                                    hout, partial, N);
    k_bnfin<<<1, 1024, 0, stream>>>(partial, NB, gamma + l * 128, beta + l * 128,
                                    ssbuf + (l + 1) * 256,
                                    bvec + ((l + 1) & 3) * 128,
                                    Wself + ((l + 1) & 3) * 16384,
                                    Wneigh + ((l + 1) & 3) * 16384,
                                    beff + ((l + 1) & 3) * 128,
                                    (l < 3) ? 1 : 0, N);
    k_pool<<<G, 256, 0, stream>>>((const uint4*)hout, gstart, gcnt, out, l);
  }
  k_div<<<(out_size + 255) / 256, 256, 0, stream>>>(out, gcnt, ssbuf, out_size);
}

// Round 7
// 875.203 us; speedup vs baseline: 1.4935x; 1.4935x over previous
//
#include <hip/hip_runtime.h>
#include <hip/hip_bf16.h>

// GraphSAGE 4-layer forward.
// R2: bf16 activations; aggregate-then-GEMM; fused MFMA GEMM + partial stats.
// R3: k_agg MLP restructure (16-lane groups x dwordx4, 8 edges/iter).
// R4: BN folded into next layer (sc -> B-tile scale, sh -> effective bias).
// R5: binned CSR build (LDS counting sort, coalesced writes); per-graph pooling.
// R6/R7: LDS-free GEMM experiments -- ~72-76us wall, schedule/occupancy-invariant;
//     compiler re-serializes VGPR-resident load hoisting (R7 VGPR=68).
// R8: agg+gemm fusion REGRESSED (gather needs full-machine TLP) -- reverted.
// R9: A-tiles staged via __builtin_amdgcn_global_load_lds (fire-and-forget,
//     compiler can't serialize; ~16KB in flight/wave). Global src pre-swizzled
//     (granule ^ row&7) so linear LDS == swizzled layout -> conflict-free ds_read.

#define EPS_BN 1e-5f
#define BSH 9                 // 512 nodes per bucket
#define BCHUNK 4096           // edges per k_bin block
#define PCAP 10240            // max edges per bucket for LDS staging (mean 8192)

typedef __attribute__((ext_vector_type(8))) short bf16x8;
typedef __attribute__((ext_vector_type(4))) float f32x4;
typedef __attribute__((address_space(1))) const void gconst_t;
typedef __attribute__((address_space(3))) void ldsv_t;

// ---------------- embedding gather -> bf16 h ---------------------------------
__global__ __launch_bounds__(256) void k_embed(const int* __restrict__ feat,
                                               const float* __restrict__ emb,
                                               __hip_bfloat162* __restrict__ hb2, int n) {
  int idx = blockIdx.x * 256 + threadIdx.x;   // one bf16x2 each
  if (idx < n * 64) {
    int i = idx >> 6, c2 = idx & 63;
    float2 v = ((const float2*)emb)[feat[i] * 64 + c2];
    hb2[idx] = __float22bfloat162_rn(v);
  }
}

// ---------------- W -> bf16, transposed: Wt[l][n][k] = W[l][k][n] ------------
__global__ __launch_bounds__(256) void k_wconv(const float* __restrict__ W,
                                               __hip_bfloat16* __restrict__ Wt, int total) {
  int idx = blockIdx.x * 256 + threadIdx.x;
  if (idx < total) {
    int l = idx >> 14, r = idx & 16383, nn = r >> 7, kk = r & 127;
    Wt[idx] = __float2bfloat16(W[(l << 14) + kk * 128 + nn]);
  }
}

// ---------------- per-graph node offsets via binary search (gid sorted) ------
__global__ void k_gcount(const int* __restrict__ gid, int* __restrict__ gcnt,
                         int* __restrict__ gstart, int n, int G) {
  int g = blockIdx.x * blockDim.x + threadIdx.x;
  if (g >= G) return;
  int lo0 = 0, hi = n;
  while (lo0 < hi) { int mid = (lo0 + hi) >> 1; if (gid[mid] < g) lo0 = mid + 1; else hi = mid; }
  int lo1 = lo0; hi = n;
  while (lo1 < hi) { int mid = (lo1 + hi) >> 1; if (gid[mid] < g + 1) lo1 = mid + 1; else hi = mid; }
  gstart[g] = lo0;
  gcnt[g] = lo1 - lo0;
}

// ---------------- bucket histogram over dst (LDS-staged) ---------------------
__global__ __launch_bounds__(256) void k_bhist(const int* __restrict__ dst,
                                               int* __restrict__ bktcnt, int m, int nbkt) {
  __shared__ int h[256];
  int t = threadIdx.x;
  h[t] = 0;
  __syncthreads();
#pragma unroll
  for (int k = 0; k < 4; ++k) {
    int idx = blockIdx.x * BCHUNK + k * 1024 + t * 4;
    if (idx + 4 <= m) {
      int4 d = *(const int4*)&dst[idx];
      atomicAdd(&h[d.x >> BSH], 1);
      atomicAdd(&h[d.y >> BSH], 1);
      atomicAdd(&h[d.z >> BSH], 1);
      atomicAdd(&h[d.w >> BSH], 1);
    } else {
      for (int e = idx; e < m && e < idx + 4; ++e) atomicAdd(&h[dst[e] >> BSH], 1);
    }
  }
  __syncthreads();
  for (int b = t; b < nbkt; b += 256)
    if (h[b]) atomicAdd(&bktcnt[b], h[b]);
}

// ---------------- scan bucket counts -> base & cursor ------------------------
__global__ void k_bscan(const int* __restrict__ bktcnt, int* __restrict__ bbase,
                        int* __restrict__ bcur, int m, int nbkt) {
  __shared__ int sh[256];
  int t = threadIdx.x;
  int v = (t < nbkt) ? bktcnt[t] : 0;
  sh[t] = v;
  __syncthreads();
  for (int o = 1; o < 256; o <<= 1) {
    int x = (t >= o) ? sh[t - o] : 0;
    __syncthreads();
    sh[t] += x;
    __syncthreads();
  }
  if (t < nbkt) { bbase[t] = sh[t] - v; bcur[t] = sh[t] - v; }
  if (t == 0) bbase[nbkt] = m;
}

// ---------------- bin edges by bucket (LDS counting sort, coalesced out) -----
__global__ __launch_bounds__(256) void k_bin(const int* __restrict__ src, const int* __restrict__ dst,
                                             int* __restrict__ bcur, uint2* __restrict__ binned,
                                             int m, int nbkt) {
  __shared__ uint2 st[BCHUNK];
  __shared__ int bcnt[256], boff[256], bres[256], wcur[256], ss[256];
  int t = threadIdx.x;
  int e0 = blockIdx.x * BCHUNK;
  int cn = min(BCHUNK, m - e0);
  int sv[16], dv[16];
  for (int b = t; b < 256; b += 256) bcnt[b] = 0;
  __syncthreads();
#pragma unroll
  for (int k = 0; k < 16; ++k) {
    int idx = e0 + k * 256 + t;
    if (idx < e0 + cn) {
      sv[k] = src[idx];
      dv[k] = dst[idx];
      atomicAdd(&bcnt[dv[k] >> BSH], 1);
    } else dv[k] = -1;
  }
  __syncthreads();
  int v = (t < nbkt) ? bcnt[t] : 0;
  ss[t] = v;
  __syncthreads();
  for (int o = 1; o < 256; o <<= 1) {
    int x = (t >= o) ? ss[t - o] : 0;
    __syncthreads();
    ss[t] += x;
    __syncthreads();
  }
  if (t < nbkt) {
    int ex = ss[t] - v;
    boff[t] = ex;
    wcur[t] = ex;
    if (v) bres[t] = atomicAdd(&bcur[t], v);
  }
  __syncthreads();
#pragma unroll
  for (int k = 0; k < 16; ++k) {
    if (dv[k] >= 0) {
      int b = dv[k] >> BSH;
      int p = atomicAdd(&wcur[b], 1);
      st[p] = make_uint2((unsigned)sv[k], (unsigned)dv[k]);
    }
  }
  __syncthreads();
  for (int j = t; j < cn; j += 256) {
    uint2 e = st[j];
    int b = (int)(e.y >> BSH);
    binned[(size_t)bres[b] + (j - boff[b])] = e;
  }
}

// ---------------- per-bucket node counts (LDS, coalesced cnt write) ----------
__global__ __launch_bounds__(256) void k_cnt(const uint2* __restrict__ binned,
                                             const int* __restrict__ bbase,
                                             int* __restrict__ cnt, int n) {
  __shared__ int h[512];
  int b = blockIdx.x, t = threadIdx.x;
  int base = b << BSH;
  int nn = min(512, n - base);
  h[t] = 0; h[t + 256] = 0;
  __syncthreads();
  int lo = bbase[b], hi = bbase[b + 1];
  for (int j = lo + t; j < hi; j += 256) atomicAdd(&h[(int)binned[j].y - base], 1);
  __syncthreads();
  if (t < nn) cnt[base + t] = h[t];
  if (t + 256 < nn) cnt[base + t + 256] = h[t + 256];
}

// ---------------- exclusive scan of cnt -> row_ptr (3 kernels) ---------------
__global__ __launch_bounds__(256) void k_scan1(const int* __restrict__ cnt,
                                               int* __restrict__ excl,
                                               int* __restrict__ blk_sums, int n) {
  __shared__ int sh[256];
  int t = threadIdx.x;
  int base = blockIdx.x * 1024 + t * 4;
  int4 v = {0, 0, 0, 0};
  if (base < n) v = *(const int4*)&cnt[base];
  int s = v.x + v.y + v.z + v.w;
  sh[t] = s;
  __syncthreads();
  for (int off = 1; off < 256; off <<= 1) {
    int x = (t >= off) ? sh[t - off] : 0;
    __syncthreads();
    sh[t] += x;
    __syncthreads();
  }
  int ex = sh[t] - s;
  if (t == 255) blk_sums[blockIdx.x] = sh[255];
  if (base < n) {
    excl[base]     = ex;
    excl[base + 1] = ex + v.x;
    excl[base + 2] = ex + v.x + v.y;
    excl[base + 3] = ex + v.x + v.y + v.z;
  }
}

__global__ void k_scan2(int* __restrict__ bs, int nb) {
  __shared__ int sh[128];
  int t = threadIdx.x;
  int v = (t < nb) ? bs[t] : 0;
  sh[t] = v;
  __syncthreads();
  for (int off = 1; off < 128; off <<= 1) {
    int x = (t >= off) ? sh[t - off] : 0;
    __syncthreads();
    sh[t] += x;
    __syncthreads();
  }
  if (t < nb) bs[t] = sh[t] - v;
}

__global__ __launch_bounds__(256) void k_scan3(int* __restrict__ rp, const int* __restrict__ bs,
                                               const int* __restrict__ cnt, int* __restrict__ cursor,
                                               float* __restrict__ deg, int n, int ne) {
  int i = blockIdx.x * 256 + threadIdx.x;
  if (i < n) {
    int r = rp[i] + bs[i >> 10];
    rp[i] = r;
    cursor[i] = r;
    int c = cnt[i];
    deg[i] = (float)(c > 0 ? c : 1);
  }
  if (i == 0) rp[n] = ne;
}

// ---------------- place edges into CSR (per-bucket LDS sort, coalesced) ------
__global__ __launch_bounds__(256) void k_place(const uint2* __restrict__ binned,
                                               const int* __restrict__ bbase,
                                               const int* __restrict__ rp,
                                               int* __restrict__ cursor,
                                               int* __restrict__ csr_src, int n) {
  int b = blockIdx.x, t = threadIdx.x;
  int base = b << BSH;
  int lo = bbase[b], hi = bbase[b + 1], m = hi - lo;
  if (m <= 0) return;
  if (m > PCAP) {                          // fallback: global-atomic scatter
    for (int j = lo + t; j < hi; j += 256) {
      uint2 e = binned[j];
      int p = atomicAdd(&cursor[(int)e.y], 1);
      csr_src[p] = (int)e.x;
    }
    return;
  }
  __shared__ int h[512], loff[512], wc[512], ss[256];
  __shared__ int stage[PCAP];
  h[t] = 0; h[t + 256] = 0;
  __syncthreads();
  for (int j = lo + t; j < hi; j += 256) atomicAdd(&h[(int)binned[j].y - base], 1);
  __syncthreads();
  int a0 = h[2 * t], a1 = h[2 * t + 1];
  int s = a0 + a1;
  ss[t] = s;
  __syncthreads();
  for (int o = 1; o < 256; o <<= 1) {
    int x = (t >= o) ? ss[t - o] : 0;
    __syncthreads();
    ss[t] += x;
    __syncthreads();
  }
  int ex = ss[t] - s;
  loff[2 * t] = ex; loff[2 * t + 1] = ex + a0;
  wc[2 * t] = ex;   wc[2 * t + 1] = ex + a0;
  __syncthreads();
  for (int j = lo + t; j < hi; j += 256) {
    uint2 e = binned[j];
    int p = atomicAdd(&wc[(int)e.y - base], 1);
    stage[p] = (int)e.x;
  }
  __syncthreads();
  int cb = rp[base];
  for (int j = t; j < m; j += 256) csr_src[cb + j] = stage[j];
}

// ---------------- init: identity BN affine + layer-0 effective bias ----------
__global__ void k_prep(const float* __restrict__ b0, float* __restrict__ ss0,
                       float* __restrict__ beff0) {
  int t = threadIdx.x;
  ss0[t] = 1.f;
  ss0[128 + t] = 0.f;
  beff0[t] = b0[t];
}

// ---------------- mean-aggregate bf16 h rows -> bf16 agg + W pre-scale -------
__device__ __forceinline__ void acc8(float* a, uint4 v) {
  float2 f;
  f = __bfloat1622float2(*(const __hip_bfloat162*)&v.x); a[0] += f.x; a[1] += f.y;
  f = __bfloat1622float2(*(const __hip_bfloat162*)&v.y); a[2] += f.x; a[3] += f.y;
  f = __bfloat1622float2(*(const __hip_bfloat162*)&v.z); a[4] += f.x; a[5] += f.y;
  f = __bfloat1622float2(*(const __hip_bfloat162*)&v.w); a[6] += f.x; a[7] += f.y;
}

__global__ __launch_bounds__(256) void k_agg(const uint4* __restrict__ hb4,
                                             const int* __restrict__ rp, const int* __restrict__ csr_src,
                                             const float* __restrict__ deg,
                                             const float* __restrict__ ssl,   // prev-layer [sc|sh]
                                             const __hip_bfloat16* __restrict__ Wst,
                                             const __hip_bfloat16* __restrict__ Wnt,
                                             __hip_bfloat16* __restrict__ Wst2,
                                             __hip_bfloat16* __restrict__ Wnt2,
                                             uint4* __restrict__ aggb4, int n) {
  int lane = threadIdx.x & 63, wid = threadIdx.x >> 6;
  int g = lane >> 4, lr = lane & 15;
  // first 16 blocks also pre-scale this layer's W by sc[k]: 4096 uint4 chunks
  if (blockIdx.x < 16) {
    int id = blockIdx.x * 256 + threadIdx.x;     // 0..4095
    int half = id >> 11;                          // 0: Ws, 1: Wn
    int ch = id & 2047;                           // uint4 chunk within 16384 el
    const uint4* Wsrc = (const uint4*)(half ? Wnt : Wst);
    uint4* Wdst = (uint4*)(half ? Wnt2 : Wst2);
    uint4 v = Wsrc[ch];
    int k0 = (ch * 8) & 127;
    __hip_bfloat162* pv = (__hip_bfloat162*)&v;
#pragma unroll
    for (int j = 0; j < 4; ++j) {
      float2 f = __bfloat1622float2(pv[j]);
      f.x *= ssl[k0 + 2 * j]; f.y *= ssl[k0 + 2 * j + 1];
      pv[j] = __float22bfloat162_rn(f);
    }
    Wdst[ch] = v;
  }
  for (int i = blockIdx.x * 4 + wid; i < n; i += gridDim.x * 4) {
    int beg = rp[i], end = rp[i + 1];
    float a[8];
#pragma unroll
    for (int c = 0; c < 8; ++c) a[c] = 0.f;
    int e = beg;
    for (; e + 8 <= end; e += 8) {        // 8 edges per wave-iteration
      int s0 = csr_src[e + g];
      int s1 = csr_src[e + 4 + g];
      uint4 v0 = hb4[(size_t)s0 * 16 + lr];
      uint4 v1 = hb4[(size_t)s1 * 16 + lr];
      acc8(a, v0);
      acc8(a, v1);
    }
    for (; e + g < end; e += 4) {         // predicated 4-edge tail
      int s = csr_src[e + g];
      uint4 v = hb4[(size_t)s * 16 + lr];
      acc8(a, v);
    }
#pragma unroll
    for (int c = 0; c < 8; ++c) {         // combine the 4 groups
      a[c] += __shfl_xor(a[c], 16, 64);
      a[c] += __shfl_xor(a[c], 32, 64);
    }
    if (g == 0) {
      float v[8];
      if (beg == end) {                   // zero-degree: cancel folded affine
#pragma unroll
        for (int c = 0; c < 8; ++c) {
          float sc = ssl[lr * 8 + c], sh = ssl[128 + lr * 8 + c];
          v[c] = (sc != 0.f) ? (-sh / sc) : 0.f;
        }
      } else {
        float invd = 1.0f / deg[i];
#pragma unroll
        for (int c = 0; c < 8; ++c) v[c] = a[c] * invd;
      }
      __hip_bfloat162 p0 = __float22bfloat162_rn(make_float2(v[0], v[1]));
      __hip_bfloat162 p1 = __float22bfloat162_rn(make_float2(v[2], v[3]));
      __hip_bfloat162 p2 = __float22bfloat162_rn(make_float2(v[4], v[5]));
      __hip_bfloat162 p3 = __float22bfloat162_rn(make_float2(v[6], v[7]));
      uint4 o;
      o.x = *(unsigned int*)&p0; o.y = *(unsigned int*)&p1;
      o.z = *(unsigned int*)&p2; o.w = *(unsigned int*)&p3;
      aggb4[(size_t)i * 16 + lr] = o;
    }
  }
}

// ------- fused MFMA GEMM: rst = PReLU(hb@Ws2 + aggb@Wn2 + beff) --------------
// R9: A-tiles staged via global_load_lds (async, 16 wave-instrs in flight).
// Global source granule pre-swizzled (c16 ^ row&7): linear LDS holds the
// swizzled layout; ds_read applies the same XOR -> conflict-free (G21/T2).
__global__ __launch_bounds__(256) void k_gemm_fused(
    const __hip_bfloat16* __restrict__ hb, const __hip_bfloat16* __restrict__ aggb,
    const __hip_bfloat16* __restrict__ Wst2, const __hip_bfloat16* __restrict__ Wnt2,
    const float* __restrict__ beff, const float* __restrict__ pw,
    __hip_bfloat16* __restrict__ hbn, float* __restrict__ partial, int n) {
  __shared__ short Ah[128 * 128];
  __shared__ short Aa[128 * 128];
  __shared__ float ls[128], lq[128];
  int t = threadIdx.x;
  int row0 = blockIdx.x * 128;
  if (t < 128) { ls[t] = 0.f; lq[t] = 0.f; }
  int w = t >> 6, lane = t & 63;

  // ---- async stage: 8 rounds x (Ah, Aa), 16B/lane, LDS dest linear ----
#pragma unroll
  for (int rd = 0; rd < 8; ++rd) {
    int Gq = rd * 256 + w * 64 + lane;       // granule id 0..2047 (16B each)
    int r = Gq >> 4;                          // local row 0..127
    int gq = (Gq & 15) ^ (r & 7);             // pre-swizzled source granule
    int grow = row0 + r;
    grow = grow < n ? grow : n - 1;           // clamp: garbage rows never used
    const __hip_bfloat16* gs = hb   + (size_t)grow * 128 + gq * 8;
    const __hip_bfloat16* ga = aggb + (size_t)grow * 128 + gq * 8;
    __builtin_amdgcn_global_load_lds((gconst_t*)gs,
        (ldsv_t*)&Ah[(rd * 256 + w * 64) * 8], 16, 0, 0);
    __builtin_amdgcn_global_load_lds((gconst_t*)ga,
        (ldsv_t*)&Aa[(rd * 256 + w * 64) * 8], 16, 0, 0);
  }
  asm volatile("s_waitcnt vmcnt(0)" ::: "memory");
  __syncthreads();

  // ---- MFMA: A from LDS (swizzled read), B from global (L2-hot) ----
  int lr16 = lane & 15, hi = lane >> 4;
  f32x4 acc[2][8];
#pragma unroll
  for (int fm = 0; fm < 2; ++fm)
#pragma unroll
    for (int fn = 0; fn < 8; ++fn) acc[fm][fn] = (f32x4){0.f, 0.f, 0.f, 0.f};

  const short* As[2] = {Ah, Aa};
  const __hip_bfloat16* Bt[2] = {Wst2, Wnt2};
#pragma unroll
  for (int s = 0; s < 2; ++s) {
    const short* A = As[s];
    const __hip_bfloat16* B = Bt[s];
#pragma unroll
    for (int ks = 0; ks < 4; ++ks) {
      bf16x8 af[2], bfr[8];
#pragma unroll
      for (int fm = 0; fm < 2; ++fm) {
        int rl = w * 32 + fm * 16 + lr16;
        int gq = (ks * 4 + hi) ^ (lr16 & 7);
        af[fm] = *(const bf16x8*)&A[rl * 128 + gq * 8];
      }
#pragma unroll
      for (int fn = 0; fn < 8; ++fn)
        bfr[fn] = *(const bf16x8*)(B + (size_t)(fn * 16 + lr16) * 128 + ks * 32 + hi * 8);
#pragma unroll
      for (int fm = 0; fm < 2; ++fm)
#pragma unroll
        for (int fn = 0; fn < 8; ++fn)
          acc[fm][fn] = __builtin_amdgcn_mfma_f32_16x16x32_bf16(af[fm], bfr[fn], acc[fm][fn], 0, 0, 0);
    }
  }

  // ---- epilogue: beff + PReLU + bf16 store + per-block stats ----
  int rb = hi * 4;             // C/D: col = lane&15, row = 4*(lane>>4)+reg  [m89]
  float sacc[8], qacc[8];
#pragma unroll
  for (int fn = 0; fn < 8; ++fn) { sacc[fn] = 0.f; qacc[fn] = 0.f; }
#pragma unroll
  for (int fm = 0; fm < 2; ++fm) {
    int rbase = row0 + w * 32 + fm * 16 + rb;
#pragma unroll
    for (int fn = 0; fn < 8; ++fn) {
      int col = fn * 16 + lr16;
      float bb = beff[col], pp = pw[col];
#pragma unroll
      for (int r = 0; r < 4; ++r) {
        int grow = rbase + r;
        if (grow < n) {
          float v = acc[fm][fn][r] + bb;
          v = v > 0.f ? v : pp * v;
          hbn[(size_t)grow * 128 + col] = __float2bfloat16(v);
          sacc[fn] += v; qacc[fn] += v * v;
        }
      }
    }
  }
#pragma unroll
  for (int fn = 0; fn < 8; ++fn) {
    int col = fn * 16 + lr16;
    atomicAdd(&ls[col], sacc[fn]);
    atomicAdd(&lq[col], qacc[fn]);
  }
  __syncthreads();
  if (t < 128) {
    partial[(size_t)blockIdx.x * 256 + t]       = ls[t];
    partial[(size_t)blockIdx.x * 256 + 128 + t] = lq[t];
  }
}

// ------------- reduce partial stats -> BN affine + next-layer eff. bias ------
// beff uses ORIGINAL fp32 weights [k][n] layout -> coalesced loads.
__global__ __launch_bounds__(1024) void k_bnfin(const float* __restrict__ partial, int nb,
                                                const float* __restrict__ gamma,
                                                const float* __restrict__ beta,
                                                float* __restrict__ ss,
                                                const float* __restrict__ bias_next,
                                                const float* __restrict__ Ws_next,
                                                const float* __restrict__ Wn_next,
                                                float* __restrict__ beff_next,
                                                int has_next, int n) {
  __shared__ float red[4][256];
  __shared__ float shv[128];
  __shared__ float bred[8][128];
  int t = threadIdx.x, c = t & 255, part = t >> 8;
  float s = 0.f;
  for (int b = part; b < nb; b += 4) s += partial[(size_t)b * 256 + c];
  red[part][c] = s;
  __syncthreads();
  if (part == 0) red[0][c] = red[0][c] + red[1][c] + red[2][c] + red[3][c];
  __syncthreads();
  if (t < 128) {
    float inv_n = 1.0f / (float)n;
    float mu = red[0][t] * inv_n;
    float var = red[0][128 + t] * inv_n - mu * mu;
    float sc = rsqrtf(var + EPS_BN) * gamma[t];
    float sh = beta[t] - mu * sc;
    ss[t] = sc;
    ss[128 + t] = sh;
    shv[t] = sh;
  }
  __syncthreads();
  if (has_next) {
    int cc = t & 127, kg = t >> 7;       // 8 k-groups x 128 channels
    float acc = 0.f;
#pragma unroll
    for (int k = kg * 16; k < kg * 16 + 16; ++k)
      acc += shv[k] * (Ws_next[k * 128 + cc] + Wn_next[k * 128 + cc]);
    bred[kg][cc] = acc;
    __syncthreads();
    if (t < 128) {
      float r = bias_next[t];
#pragma unroll
      for (int kg2 = 0; kg2 < 8; ++kg2) r += bred[kg2][t];
      beff_next[t] = r;
    }
  }
}

// ------------- per-graph pool of raw rst (bf16): one block per graph ---------
__global__ __launch_bounds__(256) void k_pool(const uint4* __restrict__ hb4,
                                              const int* __restrict__ gstart,
                                              const int* __restrict__ gcnt,
                                              float* __restrict__ out, int l) {
  __shared__ float red[4][128];
  int g = blockIdx.x;
  int i0 = gstart[g], cg = gcnt[g];
  int t = threadIdx.x, w = t >> 6, lane = t & 63;
  int gi = lane >> 4, lr = lane & 15;
  float a[8];
#pragma unroll
  for (int c = 0; c < 8; ++c) a[c] = 0.f;
#pragma unroll 2
  for (int r = w * 4 + gi; r < cg; r += 16) {    // 16 rows in flight per block
    uint4 v = hb4[(size_t)(i0 + r) * 16 + lr];
    acc8(a, v);
  }
#pragma unroll
  for (int c = 0; c < 8; ++c) {                  // combine 4 groups in wave
    a[c] += __shfl_xor(a[c], 16, 64);
    a[c] += __shfl_xor(a[c], 32, 64);
  }
  if (gi == 0) {
#pragma unroll
    for (int c = 0; c < 8; ++c) red[w][lr * 8 + c] = a[c];
  }
  __syncthreads();
  if (t < 128)
    out[(size_t)g * 512 + l * 128 + t] = red[0][t] + red[1][t] + red[2][t] + red[3][t];
}

// ------------- finalize: mean + BN affine per layer section ------------------
__global__ __launch_bounds__(256) void k_div(float* __restrict__ out, const int* __restrict__ gcnt,
                                             const float* __restrict__ ssbuf, int m) {
  int i = blockIdx.x * 256 + threadIdx.x;
  if (i < m) {
    int g = i >> 9;
    int lc = i & 511;
    int l = lc >> 7, c = lc & 127;
    const float* ss = ssbuf + (l + 1) * 256;
    int cn = gcnt[g];
    out[i] = (cn > 0) ? (out[i] / (float)cn) * ss[c] + ss[128 + c] : 0.f;
  }
}

extern "C" void kernel_launch(void* const* d_in, const int* in_sizes, int n_in,
                              void* d_out, int out_size, void* d_ws, size_t ws_size,
                              hipStream_t stream) {
  const int*   in_feat = (const int*)d_in[0];
  const int*   src     = (const int*)d_in[1];
  const int*   dst     = (const int*)d_in[2];
  const int*   gid     = (const int*)d_in[3];
  const float* emb     = (const float*)d_in[4];
  const float* Wself   = (const float*)d_in[5];
  const float* Wneigh  = (const float*)d_in[6];
  const float* bvec    = (const float*)d_in[7];
  const float* gamma   = (const float*)d_in[8];
  const float* beta    = (const float*)d_in[9];
  const float* prelu   = (const float*)d_in[10];
  const int N = in_sizes[0];
  const int E = in_sizes[1];
  const int G = out_size / 512;
  float* out = (float*)d_out;
  const int NB = (N + 127) / 128;          // gemm blocks
  const int NBKT = (N + 511) >> BSH;       // buckets (<=256 for N<=128K)

  char* p = (char*)d_ws;
  size_t off = 0;
  auto take = [&](size_t bytes) { void* r = p + off; off += (bytes + 255) & ~(size_t)255; return r; };
  __hip_bfloat16* hb0   = (__hip_bfloat16*)take((size_t)N * 128 * 2);
  __hip_bfloat16* hb1   = (__hip_bfloat16*)take((size_t)N * 128 * 2);
  __hip_bfloat16* aggb  = (__hip_bfloat16*)take((size_t)N * 128 * 2);
  __hip_bfloat16* Wst   = (__hip_bfloat16*)take((size_t)4 * 128 * 128 * 2);
  __hip_bfloat16* Wnt   = (__hip_bfloat16*)take((size_t)4 * 128 * 128 * 2);
  __hip_bfloat16* Wst2  = (__hip_bfloat16*)take((size_t)128 * 128 * 2);
  __hip_bfloat16* Wnt2  = (__hip_bfloat16*)take((size_t)128 * 128 * 2);
  float* partial        = (float*)take((size_t)NB * 256 * 4);
  float* ssbuf          = (float*)take((size_t)5 * 256 * 4);  // [l][sc|sh], l=0 identity
  float* beff           = (float*)take((size_t)4 * 128 * 4);
  uint2* binned  = (uint2*)take((size_t)E * 8);
  int*   csr_src = (int*)take((size_t)E * 4);
  int*   cnt     = (int*)take((size_t)N * 4);
  int*   rp      = (int*)take((size_t)(N + 1) * 4);
  int*   cursor  = (int*)take((size_t)N * 4);
  float* deg     = (float*)take((size_t)N * 4);
  int*   bs      = (int*)take(512);
  int*   gcnt    = (int*)take((size_t)G * 4);
  int*   gstart  = (int*)take((size_t)G * 4);
  int*   bktcnt  = (int*)take((size_t)NBKT * 4);
  int*   bbase   = (int*)take((size_t)(NBKT + 1) * 4);
  int*   bcur    = (int*)take((size_t)NBKT * 4);
  if (off > ws_size) return;

  hipMemsetAsync(bktcnt, 0, (size_t)NBKT * 4, stream);

  k_embed<<<(N * 64 + 255) / 256, 256, 0, stream>>>(in_feat, emb, (__hip_bfloat162*)hb0, N);
  k_wconv<<<(4 * 128 * 128 + 255) / 256, 256, 0, stream>>>(Wself, Wst, 4 * 128 * 128);
  k_wconv<<<(4 * 128 * 128 + 255) / 256, 256, 0, stream>>>(Wneigh, Wnt, 4 * 128 * 128);
  k_gcount<<<1, 128, 0, stream>>>(gid, gcnt, gstart, N, G);

  int nbb = (E + BCHUNK - 1) / BCHUNK;
  k_bhist<<<nbb, 256, 0, stream>>>(dst, bktcnt, E, NBKT);
  k_bscan<<<1, 256, 0, stream>>>(bktcnt, bbase, bcur, E, NBKT);
  k_bin<<<nbb, 256, 0, stream>>>(src, dst, bcur, binned, E, NBKT);
  k_cnt<<<NBKT, 256, 0, stream>>>(binned, bbase, cnt, N);
  int nsb = (N + 1023) / 1024;
  k_scan1<<<nsb, 256, 0, stream>>>(cnt, rp, bs, N);
  k_scan2<<<1, 128, 0, stream>>>(bs, nsb);
  k_scan3<<<(N + 255) / 256, 256, 0, stream>>>(rp, bs, cnt, cursor, deg, N, E);
  k_place<<<NBKT, 256, 0, stream>>>(binned, bbase, rp, cursor, csr_src, N);
  k_prep<<<1, 128, 0, stream>>>(bvec, ssbuf, beff);

  __hip_bfloat16* bufs[2] = {hb0, hb1};
  for (int l = 0; l < 4; ++l) {
    __hip_bfloat16* hin  = bufs[l & 1];
    __hip_bfloat16* hout = bufs[(l + 1) & 1];
    k_agg<<<2048, 256, 0, stream>>>((const uint4*)hin, rp, csr_src, deg,
                                    ssbuf + l * 256,
                                    Wst + l * 16384, Wnt + l * 16384, Wst2, Wnt2,
                                    (uint4*)aggb, N);
    k_gemm_fused<<<NB, 256, 0, stream>>>(hin, aggb, Wst2, Wnt2,
                                         beff + l * 128, prelu + l * 128,
                                         hout, partial, N);
    k_bnfin<<<1, 1024, 0, stream>>>(partial, NB, gamma + l * 128, beta + l * 128,
                                    ssbuf + (l + 1) * 256,
                                    bvec + ((l + 1) & 3) * 128,
                                    Wself + ((l + 1) & 3) * 16384,
                                    Wneigh + ((l + 1) & 3) * 16384,
                                    beff + ((l + 1) & 3) * 128,
                                    (l < 3) ? 1 : 0, N);
    k_pool<<<G, 256, 0, stream>>>((const uint4*)hout, gstart, gcnt, out, l);
  }
  k_div<<<(out_size + 255) / 256, 256, 0, stream>>>(out, gcnt, ssbuf, out_size);
}

// Round 8
// 855.167 us; speedup vs baseline: 1.5285x; 1.0234x over previous
//
#include <hip/hip_runtime.h>
#include <hip/hip_bf16.h>

// GraphSAGE 4-layer forward.
// R2: bf16 activations; aggregate-then-GEMM; fused MFMA GEMM + partial stats.
// R3: k_agg MLP restructure (16-lane groups x dwordx4, 8 edges/iter).
// R4: BN folded into next layer (sc -> B-tile scale, sh -> effective bias).
// R5: binned CSR build (LDS counting sort, coalesced writes); per-graph pooling.
// R6-R9: four GEMM load schemes (LDS-tile, direct, hoisted+pipelined, async
//     global_load_lds) ALL hit the same 72-76us wall at ~715 GB/s -> the limit
//     is WAVE COUNT (3136 waves on an 8192-wave machine), not per-wave MLP.
// R10: GEMM re-decomposed to 16 rows/wave: 6252 waves (~24/CU), ~100 VGPR,
//     LDS-free. Stats via 8-blocks-per-slot global atomics (196 slots).

#define EPS_BN 1e-5f
#define BSH 9                 // 512 nodes per bucket
#define BCHUNK 4096           // edges per k_bin block
#define PCAP 10240            // max edges per bucket for LDS staging (mean 8192)

typedef __attribute__((ext_vector_type(8))) short bf16x8;
typedef __attribute__((ext_vector_type(4))) float f32x4;

// ---------------- embedding gather -> bf16 h ---------------------------------
__global__ __launch_bounds__(256) void k_embed(const int* __restrict__ feat,
                                               const float* __restrict__ emb,
                                               __hip_bfloat162* __restrict__ hb2, int n) {
  int idx = blockIdx.x * 256 + threadIdx.x;   // one bf16x2 each
  if (idx < n * 64) {
    int i = idx >> 6, c2 = idx & 63;
    float2 v = ((const float2*)emb)[feat[i] * 64 + c2];
    hb2[idx] = __float22bfloat162_rn(v);
  }
}

// ---------------- W -> bf16, transposed: Wt[l][n][k] = W[l][k][n] ------------
__global__ __launch_bounds__(256) void k_wconv(const float* __restrict__ W,
                                               __hip_bfloat16* __restrict__ Wt, int total) {
  int idx = blockIdx.x * 256 + threadIdx.x;
  if (idx < total) {
    int l = idx >> 14, r = idx & 16383, nn = r >> 7, kk = r & 127;
    Wt[idx] = __float2bfloat16(W[(l << 14) + kk * 128 + nn]);
  }
}

// ---------------- per-graph node offsets via binary search (gid sorted) ------
__global__ void k_gcount(const int* __restrict__ gid, int* __restrict__ gcnt,
                         int* __restrict__ gstart, int n, int G) {
  int g = blockIdx.x * blockDim.x + threadIdx.x;
  if (g >= G) return;
  int lo0 = 0, hi = n;
  while (lo0 < hi) { int mid = (lo0 + hi) >> 1; if (gid[mid] < g) lo0 = mid + 1; else hi = mid; }
  int lo1 = lo0; hi = n;
  while (lo1 < hi) { int mid = (lo1 + hi) >> 1; if (gid[mid] < g + 1) lo1 = mid + 1; else hi = mid; }
  gstart[g] = lo0;
  gcnt[g] = lo1 - lo0;
}

// ---------------- bucket histogram over dst (LDS-staged) ---------------------
__global__ __launch_bounds__(256) void k_bhist(const int* __restrict__ dst,
                                               int* __restrict__ bktcnt, int m, int nbkt) {
  __shared__ int h[256];
  int t = threadIdx.x;
  h[t] = 0;
  __syncthreads();
#pragma unroll
  for (int k = 0; k < 4; ++k) {
    int idx = blockIdx.x * BCHUNK + k * 1024 + t * 4;
    if (idx + 4 <= m) {
      int4 d = *(const int4*)&dst[idx];
      atomicAdd(&h[d.x >> BSH], 1);
      atomicAdd(&h[d.y >> BSH], 1);
      atomicAdd(&h[d.z >> BSH], 1);
      atomicAdd(&h[d.w >> BSH], 1);
    } else {
      for (int e = idx; e < m && e < idx + 4; ++e) atomicAdd(&h[dst[e] >> BSH], 1);
    }
  }
  __syncthreads();
  for (int b = t; b < nbkt; b += 256)
    if (h[b]) atomicAdd(&bktcnt[b], h[b]);
}

// ---------------- scan bucket counts -> base & cursor ------------------------
__global__ void k_bscan(const int* __restrict__ bktcnt, int* __restrict__ bbase,
                        int* __restrict__ bcur, int m, int nbkt) {
  __shared__ int sh[256];
  int t = threadIdx.x;
  int v = (t < nbkt) ? bktcnt[t] : 0;
  sh[t] = v;
  __syncthreads();
  for (int o = 1; o < 256; o <<= 1) {
    int x = (t >= o) ? sh[t - o] : 0;
    __syncthreads();
    sh[t] += x;
    __syncthreads();
  }
  if (t < nbkt) { bbase[t] = sh[t] - v; bcur[t] = sh[t] - v; }
  if (t == 0) bbase[nbkt] = m;
}

// ---------------- bin edges by bucket (LDS counting sort, coalesced out) -----
__global__ __launch_bounds__(256) void k_bin(const int* __restrict__ src, const int* __restrict__ dst,
                                             int* __restrict__ bcur, uint2* __restrict__ binned,
                                             int m, int nbkt) {
  __shared__ uint2 st[BCHUNK];
  __shared__ int bcnt[256], boff[256], bres[256], wcur[256], ss[256];
  int t = threadIdx.x;
  int e0 = blockIdx.x * BCHUNK;
  int cn = min(BCHUNK, m - e0);
  int sv[16], dv[16];
  for (int b = t; b < 256; b += 256) bcnt[b] = 0;
  __syncthreads();
#pragma unroll
  for (int k = 0; k < 16; ++k) {
    int idx = e0 + k * 256 + t;
    if (idx < e0 + cn) {
      sv[k] = src[idx];
      dv[k] = dst[idx];
      atomicAdd(&bcnt[dv[k] >> BSH], 1);
    } else dv[k] = -1;
  }
  __syncthreads();
  int v = (t < nbkt) ? bcnt[t] : 0;
  ss[t] = v;
  __syncthreads();
  for (int o = 1; o < 256; o <<= 1) {
    int x = (t >= o) ? ss[t - o] : 0;
    __syncthreads();
    ss[t] += x;
    __syncthreads();
  }
  if (t < nbkt) {
    int ex = ss[t] - v;
    boff[t] = ex;
    wcur[t] = ex;
    if (v) bres[t] = atomicAdd(&bcur[t], v);
  }
  __syncthreads();
#pragma unroll
  for (int k = 0; k < 16; ++k) {
    if (dv[k] >= 0) {
      int b = dv[k] >> BSH;
      int p = atomicAdd(&wcur[b], 1);
      st[p] = make_uint2((unsigned)sv[k], (unsigned)dv[k]);
    }
  }
  __syncthreads();
  for (int j = t; j < cn; j += 256) {
    uint2 e = st[j];
    int b = (int)(e.y >> BSH);
    binned[(size_t)bres[b] + (j - boff[b])] = e;
  }
}

// ---------------- per-bucket node counts (LDS, coalesced cnt write) ----------
__global__ __launch_bounds__(256) void k_cnt(const uint2* __restrict__ binned,
                                             const int* __restrict__ bbase,
                                             int* __restrict__ cnt, int n) {
  __shared__ int h[512];
  int b = blockIdx.x, t = threadIdx.x;
  int base = b << BSH;
  int nn = min(512, n - base);
  h[t] = 0; h[t + 256] = 0;
  __syncthreads();
  int lo = bbase[b], hi = bbase[b + 1];
  for (int j = lo + t; j < hi; j += 256) atomicAdd(&h[(int)binned[j].y - base], 1);
  __syncthreads();
  if (t < nn) cnt[base + t] = h[t];
  if (t + 256 < nn) cnt[base + t + 256] = h[t + 256];
}

// ---------------- exclusive scan of cnt -> row_ptr (3 kernels) ---------------
__global__ __launch_bounds__(256) void k_scan1(const int* __restrict__ cnt,
                                               int* __restrict__ excl,
                                               int* __restrict__ blk_sums, int n) {
  __shared__ int sh[256];
  int t = threadIdx.x;
  int base = blockIdx.x * 1024 + t * 4;
  int4 v = {0, 0, 0, 0};
  if (base < n) v = *(const int4*)&cnt[base];
  int s = v.x + v.y + v.z + v.w;
  sh[t] = s;
  __syncthreads();
  for (int off = 1; off < 256; off <<= 1) {
    int x = (t >= off) ? sh[t - off] : 0;
    __syncthreads();
    sh[t] += x;
    __syncthreads();
  }
  int ex = sh[t] - s;
  if (t == 255) blk_sums[blockIdx.x] = sh[255];
  if (base < n) {
    excl[base]     = ex;
    excl[base + 1] = ex + v.x;
    excl[base + 2] = ex + v.x + v.y;
    excl[base + 3] = ex + v.x + v.y + v.z;
  }
}

__global__ void k_scan2(int* __restrict__ bs, int nb) {
  __shared__ int sh[128];
  int t = threadIdx.x;
  int v = (t < nb) ? bs[t] : 0;
  sh[t] = v;
  __syncthreads();
  for (int off = 1; off < 128; off <<= 1) {
    int x = (t >= off) ? sh[t - off] : 0;
    __syncthreads();
    sh[t] += x;
    __syncthreads();
  }
  if (t < nb) bs[t] = sh[t] - v;
}

__global__ __launch_bounds__(256) void k_scan3(int* __restrict__ rp, const int* __restrict__ bs,
                                               const int* __restrict__ cnt, int* __restrict__ cursor,
                                               float* __restrict__ deg, int n, int ne) {
  int i = blockIdx.x * 256 + threadIdx.x;
  if (i < n) {
    int r = rp[i] + bs[i >> 10];
    rp[i] = r;
    cursor[i] = r;
    int c = cnt[i];
    deg[i] = (float)(c > 0 ? c : 1);
  }
  if (i == 0) rp[n] = ne;
}

// ---------------- place edges into CSR (per-bucket LDS sort, coalesced) ------
__global__ __launch_bounds__(256) void k_place(const uint2* __restrict__ binned,
                                               const int* __restrict__ bbase,
                                               const int* __restrict__ rp,
                                               int* __restrict__ cursor,
                                               int* __restrict__ csr_src, int n) {
  int b = blockIdx.x, t = threadIdx.x;
  int base = b << BSH;
  int lo = bbase[b], hi = bbase[b + 1], m = hi - lo;
  if (m <= 0) return;
  if (m > PCAP) {                          // fallback: global-atomic scatter
    for (int j = lo + t; j < hi; j += 256) {
      uint2 e = binned[j];
      int p = atomicAdd(&cursor[(int)e.y], 1);
      csr_src[p] = (int)e.x;
    }
    return;
  }
  __shared__ int h[512], loff[512], wc[512], ss[256];
  __shared__ int stage[PCAP];
  h[t] = 0; h[t + 256] = 0;
  __syncthreads();
  for (int j = lo + t; j < hi; j += 256) atomicAdd(&h[(int)binned[j].y - base], 1);
  __syncthreads();
  int a0 = h[2 * t], a1 = h[2 * t + 1];
  int s = a0 + a1;
  ss[t] = s;
  __syncthreads();
  for (int o = 1; o < 256; o <<= 1) {
    int x = (t >= o) ? ss[t - o] : 0;
    __syncthreads();
    ss[t] += x;
    __syncthreads();
  }
  int ex = ss[t] - s;
  loff[2 * t] = ex; loff[2 * t + 1] = ex + a0;
  wc[2 * t] = ex;   wc[2 * t + 1] = ex + a0;
  __syncthreads();
  for (int j = lo + t; j < hi; j += 256) {
    uint2 e = binned[j];
    int p = atomicAdd(&wc[(int)e.y - base], 1);
    stage[p] = (int)e.x;
  }
  __syncthreads();
  int cb = rp[base];
  for (int j = t; j < m; j += 256) csr_src[cb + j] = stage[j];
}

// ---------------- init: identity BN affine + layer-0 effective bias ----------
__global__ void k_prep(const float* __restrict__ b0, float* __restrict__ ss0,
                       float* __restrict__ beff0) {
  int t = threadIdx.x;
  ss0[t] = 1.f;
  ss0[128 + t] = 0.f;
  beff0[t] = b0[t];
}

// ---------------- mean-aggregate bf16 h rows -> bf16 agg + W pre-scale -------
__device__ __forceinline__ void acc8(float* a, uint4 v) {
  float2 f;
  f = __bfloat1622float2(*(const __hip_bfloat162*)&v.x); a[0] += f.x; a[1] += f.y;
  f = __bfloat1622float2(*(const __hip_bfloat162*)&v.y); a[2] += f.x; a[3] += f.y;
  f = __bfloat1622float2(*(const __hip_bfloat162*)&v.z); a[4] += f.x; a[5] += f.y;
  f = __bfloat1622float2(*(const __hip_bfloat162*)&v.w); a[6] += f.x; a[7] += f.y;
}

__global__ __launch_bounds__(256) void k_agg(const uint4* __restrict__ hb4,
                                             const int* __restrict__ rp, const int* __restrict__ csr_src,
                                             const float* __restrict__ deg,
                                             const float* __restrict__ ssl,   // prev-layer [sc|sh]
                                             const __hip_bfloat16* __restrict__ Wst,
                                             const __hip_bfloat16* __restrict__ Wnt,
                                             __hip_bfloat16* __restrict__ Wst2,
                                             __hip_bfloat16* __restrict__ Wnt2,
                                             uint4* __restrict__ aggb4, int n) {
  int lane = threadIdx.x & 63, wid = threadIdx.x >> 6;
  int g = lane >> 4, lr = lane & 15;
  // first 16 blocks also pre-scale this layer's W by sc[k]: 4096 uint4 chunks
  if (blockIdx.x < 16) {
    int id = blockIdx.x * 256 + threadIdx.x;     // 0..4095
    int half = id >> 11;                          // 0: Ws, 1: Wn
    int ch = id & 2047;                           // uint4 chunk within 16384 el
    const uint4* Wsrc = (const uint4*)(half ? Wnt : Wst);
    uint4* Wdst = (uint4*)(half ? Wnt2 : Wst2);
    uint4 v = Wsrc[ch];
    int k0 = (ch * 8) & 127;
    __hip_bfloat162* pv = (__hip_bfloat162*)&v;
#pragma unroll
    for (int j = 0; j < 4; ++j) {
      float2 f = __bfloat1622float2(pv[j]);
      f.x *= ssl[k0 + 2 * j]; f.y *= ssl[k0 + 2 * j + 1];
      pv[j] = __float22bfloat162_rn(f);
    }
    Wdst[ch] = v;
  }
  for (int i = blockIdx.x * 4 + wid; i < n; i += gridDim.x * 4) {
    int beg = rp[i], end = rp[i + 1];
    float a[8];
#pragma unroll
    for (int c = 0; c < 8; ++c) a[c] = 0.f;
    int e = beg;
    for (; e + 8 <= end; e += 8) {        // 8 edges per wave-iteration
      int s0 = csr_src[e + g];
      int s1 = csr_src[e + 4 + g];
      uint4 v0 = hb4[(size_t)s0 * 16 + lr];
      uint4 v1 = hb4[(size_t)s1 * 16 + lr];
      acc8(a, v0);
      acc8(a, v1);
    }
    for (; e + g < end; e += 4) {         // predicated 4-edge tail
      int s = csr_src[e + g];
      uint4 v = hb4[(size_t)s * 16 + lr];
      acc8(a, v);
    }
#pragma unroll
    for (int c = 0; c < 8; ++c) {         // combine the 4 groups
      a[c] += __shfl_xor(a[c], 16, 64);
      a[c] += __shfl_xor(a[c], 32, 64);
    }
    if (g == 0) {
      float v[8];
      if (beg == end) {                   // zero-degree: cancel folded affine
#pragma unroll
        for (int c = 0; c < 8; ++c) {
          float sc = ssl[lr * 8 + c], sh = ssl[128 + lr * 8 + c];
          v[c] = (sc != 0.f) ? (-sh / sc) : 0.f;
        }
      } else {
        float invd = 1.0f / deg[i];
#pragma unroll
        for (int c = 0; c < 8; ++c) v[c] = a[c] * invd;
      }
      __hip_bfloat162 p0 = __float22bfloat162_rn(make_float2(v[0], v[1]));
      __hip_bfloat162 p1 = __float22bfloat162_rn(make_float2(v[2], v[3]));
      __hip_bfloat162 p2 = __float22bfloat162_rn(make_float2(v[4], v[5]));
      __hip_bfloat162 p3 = __float22bfloat162_rn(make_float2(v[6], v[7]));
      uint4 o;
      o.x = *(unsigned int*)&p0; o.y = *(unsigned int*)&p1;
      o.z = *(unsigned int*)&p2; o.w = *(unsigned int*)&p3;
      aggb4[(size_t)i * 16 + lr] = o;
    }
  }
}

// ------- fused MFMA GEMM: rst = PReLU(hb@Ws2 + aggb@Wn2 + beff) --------------
// R10: 16 rows per wave, LDS-free, 6252 waves (~24/CU) -- TLP carries the
// memory concurrency. Stats: LDS reduce, then 8 blocks share a global slot.
__global__ __launch_bounds__(256, 5) void k_gemm_fused(
    const __hip_bfloat16* __restrict__ hb, const __hip_bfloat16* __restrict__ aggb,
    const __hip_bfloat16* __restrict__ Wst2, const __hip_bfloat16* __restrict__ Wnt2,
    const float* __restrict__ beff, const float* __restrict__ pw,
    __hip_bfloat16* __restrict__ hbn, float* __restrict__ partial, int n) {
  __shared__ float ls[128], lq[128];
  int t = threadIdx.x;
  int w = t >> 6, lane = t & 63;
  int lr16 = lane & 15, hi = lane >> 4, lk8 = hi * 8;
  int wrow0 = blockIdx.x * 64 + (w << 4);   // this wave's 16-row strip
  if (t < 128) { ls[t] = 0.f; lq[t] = 0.f; }
  __syncthreads();

  int ar = wrow0 + lr16;
  int arc = ar < n ? ar : n - 1;            // clamp: garbage rows never stored

  const __hip_bfloat16* As[2] = {hb, aggb};
  const __hip_bfloat16* Bt[2] = {Wst2, Wnt2};

  bf16x8 af[2][4];
#pragma unroll
  for (int s = 0; s < 2; ++s)
#pragma unroll
    for (int ks = 0; ks < 4; ++ks)
      af[s][ks] = *(const bf16x8*)(As[s] + (size_t)arc * 128 + ks * 32 + lk8);

  f32x4 acc[8];
#pragma unroll
  for (int fn = 0; fn < 8; ++fn) acc[fn] = (f32x4){0.f, 0.f, 0.f, 0.f};

#pragma unroll
  for (int p = 0; p < 8; ++p) {
    int s = p >> 2, ks = p & 3;
    const __hip_bfloat16* B = Bt[s];
    bf16x8 bfr[8];
#pragma unroll
    for (int fn = 0; fn < 8; ++fn)
      bfr[fn] = *(const bf16x8*)(B + (size_t)(fn * 16 + lr16) * 128 + ks * 32 + lk8);
#pragma unroll
    for (int fn = 0; fn < 8; ++fn)
      acc[fn] = __builtin_amdgcn_mfma_f32_16x16x32_bf16(af[s][ks], bfr[fn], acc[fn], 0, 0, 0);
  }

  // ---- epilogue: beff + PReLU + bf16 store + stats ----
  int rbase = wrow0 + hi * 4;  // C/D: col = lane&15, row = 4*(lane>>4)+reg  [m89]
  float sacc[8], qacc[8];
#pragma unroll
  for (int fn = 0; fn < 8; ++fn) { sacc[fn] = 0.f; qacc[fn] = 0.f; }
#pragma unroll
  for (int fn = 0; fn < 8; ++fn) {
    int col = fn * 16 + lr16;
    float bb = beff[col], pp = pw[col];
#pragma unroll
    for (int r = 0; r < 4; ++r) {
      int grow = rbase + r;
      if (grow < n) {
        float v = acc[fn][r] + bb;
        v = v > 0.f ? v : pp * v;
        hbn[(size_t)grow * 128 + col] = __float2bfloat16(v);
        sacc[fn] += v; qacc[fn] += v * v;
      }
    }
  }
#pragma unroll
  for (int fn = 0; fn < 8; ++fn) {
    int col = fn * 16 + lr16;
    atomicAdd(&ls[col], sacc[fn]);
    atomicAdd(&lq[col], qacc[fn]);
  }
  __syncthreads();
  if (t < 128) {
    float* pp = partial + (size_t)(blockIdx.x >> 3) * 256;
    atomicAdd(&pp[t], ls[t]);
    atomicAdd(&pp[128 + t], lq[t]);
  }
}

// ------------- reduce partial stats -> BN affine + next-layer eff. bias ------
// beff uses ORIGINAL fp32 weights [k][n] layout -> coalesced loads.
__global__ __launch_bounds__(1024) void k_bnfin(const float* __restrict__ partial, int nb,
                                                const float* __restrict__ gamma,
                                                const float* __restrict__ beta,
                                                float* __restrict__ ss,
                                                const float* __restrict__ bias_next,
                                                const float* __restrict__ Ws_next,
                                                const float* __restrict__ Wn_next,
                                                float* __restrict__ beff_next,
                                                int has_next, int n) {
  __shared__ float red[4][256];
  __shared__ float shv[128];
  __shared__ float bred[8][128];
  int t = threadIdx.x, c = t & 255, part = t >> 8;
  float s = 0.f;
  for (int b = part; b < nb; b += 4) s += partial[(size_t)b * 256 + c];
  red[part][c] = s;
  __syncthreads();
  if (part == 0) red[0][c] = red[0][c] + red[1][c] + red[2][c] + red[3][c];
  __syncthreads();
  if (t < 128) {
    float inv_n = 1.0f / (float)n;
    float mu = red[0][t] * inv_n;
    float var = red[0][128 + t] * inv_n - mu * mu;
    float sc = rsqrtf(var + EPS_BN) * gamma[t];
    float sh = beta[t] - mu * sc;
    ss[t] = sc;
    ss[128 + t] = sh;
    shv[t] = sh;
  }
  __syncthreads();
  if (has_next) {
    int cc = t & 127, kg = t >> 7;       // 8 k-groups x 128 channels
    float acc = 0.f;
#pragma unroll
    for (int k = kg * 16; k < kg * 16 + 16; ++k)
      acc += shv[k] * (Ws_next[k * 128 + cc] + Wn_next[k * 128 + cc]);
    bred[kg][cc] = acc;
    __syncthreads();
    if (t < 128) {
      float r = bias_next[t];
#pragma unroll
      for (int kg2 = 0; kg2 < 8; ++kg2) r += bred[kg2][t];
      beff_next[t] = r;
    }
  }
}

// ------------- per-graph pool of raw rst (bf16): one block per graph ---------
__global__ __launch_bounds__(256) void k_pool(const uint4* __restrict__ hb4,
                                              const int* __restrict__ gstart,
                                              const int* __restrict__ gcnt,
                                              float* __restrict__ out, int l) {
  __shared__ float red[4][128];
  int g = blockIdx.x;
  int i0 = gstart[g], cg = gcnt[g];
  int t = threadIdx.x, w = t >> 6, lane = t & 63;
  int gi = lane >> 4, lr = lane & 15;
  float a[8];
#pragma unroll
  for (int c = 0; c < 8; ++c) a[c] = 0.f;
#pragma unroll 2
  for (int r = w * 4 + gi; r < cg; r += 16) {    // 16 rows in flight per block
    uint4 v = hb4[(size_t)(i0 + r) * 16 + lr];
    acc8(a, v);
  }
#pragma unroll
  for (int c = 0; c < 8; ++c) {                  // combine 4 groups in wave
    a[c] += __shfl_xor(a[c], 16, 64);
    a[c] += __shfl_xor(a[c], 32, 64);
  }
  if (gi == 0) {
#pragma unroll
    for (int c = 0; c < 8; ++c) red[w][lr * 8 + c] = a[c];
  }
  __syncthreads();
  if (t < 128)
    out[(size_t)g * 512 + l * 128 + t] = red[0][t] + red[1][t] + red[2][t] + red[3][t];
}

// ------------- finalize: mean + BN affine per layer section ------------------
__global__ __launch_bounds__(256) void k_div(float* __restrict__ out, const int* __restrict__ gcnt,
                                             const float* __restrict__ ssbuf, int m) {
  int i = blockIdx.x * 256 + threadIdx.x;
  if (i < m) {
    int g = i >> 9;
    int lc = i & 511;
    int l = lc >> 7, c = lc & 127;
    const float* ss = ssbuf + (l + 1) * 256;
    int cn = gcnt[g];
    out[i] = (cn > 0) ? (out[i] / (float)cn) * ss[c] + ss[128 + c] : 0.f;
  }
}

extern "C" void kernel_launch(void* const* d_in, const int* in_sizes, int n_in,
                              void* d_out, int out_size, void* d_ws, size_t ws_size,
                              hipStream_t stream) {
  const int*   in_feat = (const int*)d_in[0];
  const int*   src     = (const int*)d_in[1];
  const int*   dst     = (const int*)d_in[2];
  const int*   gid     = (const int*)d_in[3];
  const float* emb     = (const float*)d_in[4];
  const float* Wself   = (const float*)d_in[5];
  const float* Wneigh  = (const float*)d_in[6];
  const float* bvec    = (const float*)d_in[7];
  const float* gamma   = (const float*)d_in[8];
  const float* beta    = (const float*)d_in[9];
  const float* prelu   = (const float*)d_in[10];
  const int N = in_sizes[0];
  const int E = in_sizes[1];
  const int G = out_size / 512;
  float* out = (float*)d_out;
  const int NBg = (N + 63) / 64;           // gemm blocks (64 rows each)
  const int NP = (NBg + 7) / 8;            // partial slots (8 blocks/slot)
  const int NBKT = (N + 511) >> BSH;       // buckets (<=256 for N<=128K)

  char* p = (char*)d_ws;
  size_t off = 0;
  auto take = [&](size_t bytes) { void* r = p + off; off += (bytes + 255) & ~(size_t)255; return r; };
  __hip_bfloat16* hb0   = (__hip_bfloat16*)take((size_t)N * 128 * 2);
  __hip_bfloat16* hb1   = (__hip_bfloat16*)take((size_t)N * 128 * 2);
  __hip_bfloat16* aggb  = (__hip_bfloat16*)take((size_t)N * 128 * 2);
  __hip_bfloat16* Wst   = (__hip_bfloat16*)take((size_t)4 * 128 * 128 * 2);
  __hip_bfloat16* Wnt   = (__hip_bfloat16*)take((size_t)4 * 128 * 128 * 2);
  __hip_bfloat16* Wst2  = (__hip_bfloat16*)take((size_t)128 * 128 * 2);
  __hip_bfloat16* Wnt2  = (__hip_bfloat16*)take((size_t)128 * 128 * 2);
  float* partial        = (float*)take((size_t)NP * 256 * 4);
  float* ssbuf          = (float*)take((size_t)5 * 256 * 4);  // [l][sc|sh], l=0 identity
  float* beff           = (float*)take((size_t)4 * 128 * 4);
  uint2* binned  = (uint2*)take((size_t)E * 8);
  int*   csr_src = (int*)take((size_t)E * 4);
  int*   cnt     = (int*)take((size_t)N * 4);
  int*   rp      = (int*)take((size_t)(N + 1) * 4);
  int*   cursor  = (int*)take((size_t)N * 4);
  float* deg     = (float*)take((size_t)N * 4);
  int*   bs      = (int*)take(512);
  int*   gcnt    = (int*)take((size_t)G * 4);
  int*   gstart  = (int*)take((size_t)G * 4);
  int*   bktcnt  = (int*)take((size_t)NBKT * 4);
  int*   bbase   = (int*)take((size_t)(NBKT + 1) * 4);
  int*   bcur    = (int*)take((size_t)NBKT * 4);
  if (off > ws_size) return;

  hipMemsetAsync(bktcnt, 0, (size_t)NBKT * 4, stream);

  k_embed<<<(N * 64 + 255) / 256, 256, 0, stream>>>(in_feat, emb, (__hip_bfloat162*)hb0, N);
  k_wconv<<<(4 * 128 * 128 + 255) / 256, 256, 0, stream>>>(Wself, Wst, 4 * 128 * 128);
  k_wconv<<<(4 * 128 * 128 + 255) / 256, 256, 0, stream>>>(Wneigh, Wnt, 4 * 128 * 128);
  k_gcount<<<1, 128, 0, stream>>>(gid, gcnt, gstart, N, G);

  int nbb = (E + BCHUNK - 1) / BCHUNK;
  k_bhist<<<nbb, 256, 0, stream>>>(dst, bktcnt, E, NBKT);
  k_bscan<<<1, 256, 0, stream>>>(bktcnt, bbase, bcur, E, NBKT);
  k_bin<<<nbb, 256, 0, stream>>>(src, dst, bcur, binned, E, NBKT);
  k_cnt<<<NBKT, 256, 0, stream>>>(binned, bbase, cnt, N);
  int nsb = (N + 1023) / 1024;
  k_scan1<<<nsb, 256, 0, stream>>>(cnt, rp, bs, N);
  k_scan2<<<1, 128, 0, stream>>>(bs, nsb);
  k_scan3<<<(N + 255) / 256, 256, 0, stream>>>(rp, bs, cnt, cursor, deg, N, E);
  k_place<<<NBKT, 256, 0, stream>>>(binned, bbase, rp, cursor, csr_src, N);
  k_prep<<<1, 128, 0, stream>>>(bvec, ssbuf, beff);

  __hip_bfloat16* bufs[2] = {hb0, hb1};
  for (int l = 0; l < 4; ++l) {
    __hip_bfloat16* hin  = bufs[l & 1];
    __hip_bfloat16* hout = bufs[(l + 1) & 1];
    k_agg<<<2048, 256, 0, stream>>>((const uint4*)hin, rp, csr_src, deg,
                                    ssbuf + l * 256,
                                    Wst + l * 16384, Wnt + l * 16384, Wst2, Wnt2,
                                    (uint4*)aggb, N);
    hipMemsetAsync(partial, 0, (size_t)NP * 256 * 4, stream);
    k_gemm_fused<<<NBg, 256, 0, stream>>>(hin, aggb, Wst2, Wnt2,
                                          beff + l * 128, prelu + l * 128,
                                          hout, partial, N);
    k_bnfin<<<1, 1024, 0, stream>>>(partial, NP, gamma + l * 128, beta + l * 128,
                                    ssbuf + (l + 1) * 256,
                                    bvec + ((l + 1) & 3) * 128,
                                    Wself + ((l + 1) & 3) * 16384,
                                    Wneigh + ((l + 1) & 3) * 16384,
                                    beff + ((l + 1) & 3) * 128,
                                    (l < 3) ? 1 : 0, N);
    k_pool<<<G, 256, 0, stream>>>((const uint4*)hout, gstart, gcnt, out, l);
  }
  k_div<<<(out_size + 255) / 256, 256, 0, stream>>>(out, gcnt, ssbuf, out_size);
}

// Round 9
// 782.264 us; speedup vs baseline: 1.6710x; 1.0932x over previous
//
#include <hip/hip_runtime.h>
#include <hip/hip_bf16.h>

// GraphSAGE 4-layer forward.
// R2: bf16 activations; aggregate-then-GEMM; fused MFMA GEMM + partial stats.
// R3: k_agg MLP restructure (16-lane groups x dwordx4, 8 edges/iter).
// R4: BN folded into next layer (sc -> B-tile scale, sh -> effective bias).
// R5: binned CSR build (LDS counting sort, coalesced writes).
// R6-R10: GEMM wall study -- five load schemes (LDS-tile, direct, hoisted,
//     async global_load_lds, 16-row/wave TLP) pin at ~72us minimum (R9 best);
//     occupancy/ILP/schedule-invariant. R10 found k_bnfin's 784-slot scan
//     was a hidden ~25us/layer serial cost.
// R11: R9 GEMM + 98 stat slots (8 blocks/slot atomics) + per-graph pooling
//     FUSED into the GEMM epilogue (gid-sorted rows: 84% of blocks are
//     single-graph -> pool sum == stat sum ls[]); k_pool deleted; last-layer
//     hbn store skipped.

#define EPS_BN 1e-5f
#define BSH 9                 // 512 nodes per bucket
#define BCHUNK 4096           // edges per k_bin block
#define PCAP 10240            // max edges per bucket for LDS staging (mean 8192)
#define POOLG 4               // LDS pool slots per gemm block (graph span cap)

typedef __attribute__((ext_vector_type(8))) short bf16x8;
typedef __attribute__((ext_vector_type(4))) float f32x4;
typedef __attribute__((address_space(1))) const void gconst_t;
typedef __attribute__((address_space(3))) void ldsv_t;

// ---------------- embedding gather -> bf16 h ---------------------------------
__global__ __launch_bounds__(256) void k_embed(const int* __restrict__ feat,
                                               const float* __restrict__ emb,
                                               __hip_bfloat162* __restrict__ hb2, int n) {
  int idx = blockIdx.x * 256 + threadIdx.x;   // one bf16x2 each
  if (idx < n * 64) {
    int i = idx >> 6, c2 = idx & 63;
    float2 v = ((const float2*)emb)[feat[i] * 64 + c2];
    hb2[idx] = __float22bfloat162_rn(v);
  }
}

// ---------------- W -> bf16, transposed: Wt[l][n][k] = W[l][k][n] ------------
__global__ __launch_bounds__(256) void k_wconv(const float* __restrict__ W,
                                               __hip_bfloat16* __restrict__ Wt, int total) {
  int idx = blockIdx.x * 256 + threadIdx.x;
  if (idx < total) {
    int l = idx >> 14, r = idx & 16383, nn = r >> 7, kk = r & 127;
    Wt[idx] = __float2bfloat16(W[(l << 14) + kk * 128 + nn]);
  }
}

// ---------------- per-graph node offsets via binary search (gid sorted) ------
__global__ void k_gcount(const int* __restrict__ gid, int* __restrict__ gcnt,
                         int* __restrict__ gstart, int n, int G) {
  int g = blockIdx.x * blockDim.x + threadIdx.x;
  if (g >= G) return;
  int lo0 = 0, hi = n;
  while (lo0 < hi) { int mid = (lo0 + hi) >> 1; if (gid[mid] < g) lo0 = mid + 1; else hi = mid; }
  int lo1 = lo0; hi = n;
  while (lo1 < hi) { int mid = (lo1 + hi) >> 1; if (gid[mid] < g + 1) lo1 = mid + 1; else hi = mid; }
  gstart[g] = lo0;
  gcnt[g] = lo1 - lo0;
}

// ---------------- bucket histogram over dst (LDS-staged) ---------------------
__global__ __launch_bounds__(256) void k_bhist(const int* __restrict__ dst,
                                               int* __restrict__ bktcnt, int m, int nbkt) {
  __shared__ int h[256];
  int t = threadIdx.x;
  h[t] = 0;
  __syncthreads();
#pragma unroll
  for (int k = 0; k < 4; ++k) {
    int idx = blockIdx.x * BCHUNK + k * 1024 + t * 4;
    if (idx + 4 <= m) {
      int4 d = *(const int4*)&dst[idx];
      atomicAdd(&h[d.x >> BSH], 1);
      atomicAdd(&h[d.y >> BSH], 1);
      atomicAdd(&h[d.z >> BSH], 1);
      atomicAdd(&h[d.w >> BSH], 1);
    } else {
      for (int e = idx; e < m && e < idx + 4; ++e) atomicAdd(&h[dst[e] >> BSH], 1);
    }
  }
  __syncthreads();
  for (int b = t; b < nbkt; b += 256)
    if (h[b]) atomicAdd(&bktcnt[b], h[b]);
}

// ---------------- scan bucket counts -> base & cursor ------------------------
__global__ void k_bscan(const int* __restrict__ bktcnt, int* __restrict__ bbase,
                        int* __restrict__ bcur, int m, int nbkt) {
  __shared__ int sh[256];
  int t = threadIdx.x;
  int v = (t < nbkt) ? bktcnt[t] : 0;
  sh[t] = v;
  __syncthreads();
  for (int o = 1; o < 256; o <<= 1) {
    int x = (t >= o) ? sh[t - o] : 0;
    __syncthreads();
    sh[t] += x;
    __syncthreads();
  }
  if (t < nbkt) { bbase[t] = sh[t] - v; bcur[t] = sh[t] - v; }
  if (t == 0) bbase[nbkt] = m;
}

// ---------------- bin edges by bucket (LDS counting sort, coalesced out) -----
__global__ __launch_bounds__(256) void k_bin(const int* __restrict__ src, const int* __restrict__ dst,
                                             int* __restrict__ bcur, uint2* __restrict__ binned,
                                             int m, int nbkt) {
  __shared__ uint2 st[BCHUNK];
  __shared__ int bcnt[256], boff[256], bres[256], wcur[256], ss[256];
  int t = threadIdx.x;
  int e0 = blockIdx.x * BCHUNK;
  int cn = min(BCHUNK, m - e0);
  int sv[16], dv[16];
  for (int b = t; b < 256; b += 256) bcnt[b] = 0;
  __syncthreads();
#pragma unroll
  for (int k = 0; k < 16; ++k) {
    int idx = e0 + k * 256 + t;
    if (idx < e0 + cn) {
      sv[k] = src[idx];
      dv[k] = dst[idx];
      atomicAdd(&bcnt[dv[k] >> BSH], 1);
    } else dv[k] = -1;
  }
  __syncthreads();
  int v = (t < nbkt) ? bcnt[t] : 0;
  ss[t] = v;
  __syncthreads();
  for (int o = 1; o < 256; o <<= 1) {
    int x = (t >= o) ? ss[t - o] : 0;
    __syncthreads();
    ss[t] += x;
    __syncthreads();
  }
  if (t < nbkt) {
    int ex = ss[t] - v;
    boff[t] = ex;
    wcur[t] = ex;
    if (v) bres[t] = atomicAdd(&bcur[t], v);
  }
  __syncthreads();
#pragma unroll
  for (int k = 0; k < 16; ++k) {
    if (dv[k] >= 0) {
      int b = dv[k] >> BSH;
      int p = atomicAdd(&wcur[b], 1);
      st[p] = make_uint2((unsigned)sv[k], (unsigned)dv[k]);
    }
  }
  __syncthreads();
  for (int j = t; j < cn; j += 256) {
    uint2 e = st[j];
    int b = (int)(e.y >> BSH);
    binned[(size_t)bres[b] + (j - boff[b])] = e;
  }
}

// ---------------- per-bucket node counts (LDS, coalesced cnt write) ----------
__global__ __launch_bounds__(256) void k_cnt(const uint2* __restrict__ binned,
                                             const int* __restrict__ bbase,
                                             int* __restrict__ cnt, int n) {
  __shared__ int h[512];
  int b = blockIdx.x, t = threadIdx.x;
  int base = b << BSH;
  int nn = min(512, n - base);
  h[t] = 0; h[t + 256] = 0;
  __syncthreads();
  int lo = bbase[b], hi = bbase[b + 1];
  for (int j = lo + t; j < hi; j += 256) atomicAdd(&h[(int)binned[j].y - base], 1);
  __syncthreads();
  if (t < nn) cnt[base + t] = h[t];
  if (t + 256 < nn) cnt[base + t + 256] = h[t + 256];
}

// ---------------- exclusive scan of cnt -> row_ptr (3 kernels) ---------------
__global__ __launch_bounds__(256) void k_scan1(const int* __restrict__ cnt,
                                               int* __restrict__ excl,
                                               int* __restrict__ blk_sums, int n) {
  __shared__ int sh[256];
  int t = threadIdx.x;
  int base = blockIdx.x * 1024 + t * 4;
  int4 v = {0, 0, 0, 0};
  if (base < n) v = *(const int4*)&cnt[base];
  int s = v.x + v.y + v.z + v.w;
  sh[t] = s;
  __syncthreads();
  for (int off = 1; off < 256; off <<= 1) {
    int x = (t >= off) ? sh[t - off] : 0;
    __syncthreads();
    sh[t] += x;
    __syncthreads();
  }
  int ex = sh[t] - s;
  if (t == 255) blk_sums[blockIdx.x] = sh[255];
  if (base < n) {
    excl[base]     = ex;
    excl[base + 1] = ex + v.x;
    excl[base + 2] = ex + v.x + v.y;
    excl[base + 3] = ex + v.x + v.y + v.z;
  }
}

__global__ void k_scan2(int* __restrict__ bs, int nb) {
  __shared__ int sh[128];
  int t = threadIdx.x;
  int v = (t < nb) ? bs[t] : 0;
  sh[t] = v;
  __syncthreads();
  for (int off = 1; off < 128; off <<= 1) {
    int x = (t >= off) ? sh[t - off] : 0;
    __syncthreads();
    sh[t] += x;
    __syncthreads();
  }
  if (t < nb) bs[t] = sh[t] - v;
}

__global__ __launch_bounds__(256) void k_scan3(int* __restrict__ rp, const int* __restrict__ bs,
                                               const int* __restrict__ cnt, int* __restrict__ cursor,
                                               float* __restrict__ deg, int n, int ne) {
  int i = blockIdx.x * 256 + threadIdx.x;
  if (i < n) {
    int r = rp[i] + bs[i >> 10];
    rp[i] = r;
    cursor[i] = r;
    int c = cnt[i];
    deg[i] = (float)(c > 0 ? c : 1);
  }
  if (i == 0) rp[n] = ne;
}

// ---------------- place edges into CSR (per-bucket LDS sort, coalesced) ------
__global__ __launch_bounds__(256) void k_place(const uint2* __restrict__ binned,
                                               const int* __restrict__ bbase,
                                               const int* __restrict__ rp,
                                               int* __restrict__ cursor,
                                               int* __restrict__ csr_src, int n) {
  int b = blockIdx.x, t = threadIdx.x;
  int base = b << BSH;
  int lo = bbase[b], hi = bbase[b + 1], m = hi - lo;
  if (m <= 0) return;
  if (m > PCAP) {                          // fallback: global-atomic scatter
    for (int j = lo + t; j < hi; j += 256) {
      uint2 e = binned[j];
      int p = atomicAdd(&cursor[(int)e.y], 1);
      csr_src[p] = (int)e.x;
    }
    return;
  }
  __shared__ int h[512], loff[512], wc[512], ss[256];
  __shared__ int stage[PCAP];
  h[t] = 0; h[t + 256] = 0;
  __syncthreads();
  for (int j = lo + t; j < hi; j += 256) atomicAdd(&h[(int)binned[j].y - base], 1);
  __syncthreads();
  int a0 = h[2 * t], a1 = h[2 * t + 1];
  int s = a0 + a1;
  ss[t] = s;
  __syncthreads();
  for (int o = 1; o < 256; o <<= 1) {
    int x = (t >= o) ? ss[t - o] : 0;
    __syncthreads();
    ss[t] += x;
    __syncthreads();
  }
  int ex = ss[t] - s;
  loff[2 * t] = ex; loff[2 * t + 1] = ex + a0;
  wc[2 * t] = ex;   wc[2 * t + 1] = ex + a0;
  __syncthreads();
  for (int j = lo + t; j < hi; j += 256) {
    uint2 e = binned[j];
    int p = atomicAdd(&wc[(int)e.y - base], 1);
    stage[p] = (int)e.x;
  }
  __syncthreads();
  int cb = rp[base];
  for (int j = t; j < m; j += 256) csr_src[cb + j] = stage[j];
}

// ---------------- init: identity BN affine + layer-0 effective bias ----------
__global__ void k_prep(const float* __restrict__ b0, float* __restrict__ ss0,
                       float* __restrict__ beff0) {
  int t = threadIdx.x;
  ss0[t] = 1.f;
  ss0[128 + t] = 0.f;
  beff0[t] = b0[t];
}

// ---------------- mean-aggregate bf16 h rows -> bf16 agg + W pre-scale -------
__device__ __forceinline__ void acc8(float* a, uint4 v) {
  float2 f;
  f = __bfloat1622float2(*(const __hip_bfloat162*)&v.x); a[0] += f.x; a[1] += f.y;
  f = __bfloat1622float2(*(const __hip_bfloat162*)&v.y); a[2] += f.x; a[3] += f.y;
  f = __bfloat1622float2(*(const __hip_bfloat162*)&v.z); a[4] += f.x; a[5] += f.y;
  f = __bfloat1622float2(*(const __hip_bfloat162*)&v.w); a[6] += f.x; a[7] += f.y;
}

__global__ __launch_bounds__(256) void k_agg(const uint4* __restrict__ hb4,
                                             const int* __restrict__ rp, const int* __restrict__ csr_src,
                                             const float* __restrict__ deg,
                                             const float* __restrict__ ssl,   // prev-layer [sc|sh]
                                             const __hip_bfloat16* __restrict__ Wst,
                                             const __hip_bfloat16* __restrict__ Wnt,
                                             __hip_bfloat16* __restrict__ Wst2,
                                             __hip_bfloat16* __restrict__ Wnt2,
                                             uint4* __restrict__ aggb4, int n) {
  int lane = threadIdx.x & 63, wid = threadIdx.x >> 6;
  int g = lane >> 4, lr = lane & 15;
  // first 16 blocks also pre-scale this layer's W by sc[k]: 4096 uint4 chunks
  if (blockIdx.x < 16) {
    int id = blockIdx.x * 256 + threadIdx.x;     // 0..4095
    int half = id >> 11;                          // 0: Ws, 1: Wn
    int ch = id & 2047;                           // uint4 chunk within 16384 el
    const uint4* Wsrc = (const uint4*)(half ? Wnt : Wst);
    uint4* Wdst = (uint4*)(half ? Wnt2 : Wst2);
    uint4 v = Wsrc[ch];
    int k0 = (ch * 8) & 127;
    __hip_bfloat162* pv = (__hip_bfloat162*)&v;
#pragma unroll
    for (int j = 0; j < 4; ++j) {
      float2 f = __bfloat1622float2(pv[j]);
      f.x *= ssl[k0 + 2 * j]; f.y *= ssl[k0 + 2 * j + 1];
      pv[j] = __float22bfloat162_rn(f);
    }
    Wdst[ch] = v;
  }
  for (int i = blockIdx.x * 4 + wid; i < n; i += gridDim.x * 4) {
    int beg = rp[i], end = rp[i + 1];
    float a[8];
#pragma unroll
    for (int c = 0; c < 8; ++c) a[c] = 0.f;
    int e = beg;
    for (; e + 8 <= end; e += 8) {        // 8 edges per wave-iteration
      int s0 = csr_src[e + g];
      int s1 = csr_src[e + 4 + g];
      uint4 v0 = hb4[(size_t)s0 * 16 + lr];
      uint4 v1 = hb4[(size_t)s1 * 16 + lr];
      acc8(a, v0);
      acc8(a, v1);
    }
    for (; e + g < end; e += 4) {         // predicated 4-edge tail
      int s = csr_src[e + g];
      uint4 v = hb4[(size_t)s * 16 + lr];
      acc8(a, v);
    }
#pragma unroll
    for (int c = 0; c < 8; ++c) {         // combine the 4 groups
      a[c] += __shfl_xor(a[c], 16, 64);
      a[c] += __shfl_xor(a[c], 32, 64);
    }
    if (g == 0) {
      float v[8];
      if (beg == end) {                   // zero-degree: cancel folded affine
#pragma unroll
        for (int c = 0; c < 8; ++c) {
          float sc = ssl[lr * 8 + c], sh = ssl[128 + lr * 8 + c];
          v[c] = (sc != 0.f) ? (-sh / sc) : 0.f;
        }
      } else {
        float invd = 1.0f / deg[i];
#pragma unroll
        for (int c = 0; c < 8; ++c) v[c] = a[c] * invd;
      }
      __hip_bfloat162 p0 = __float22bfloat162_rn(make_float2(v[0], v[1]));
      __hip_bfloat162 p1 = __float22bfloat162_rn(make_float2(v[2], v[3]));
      __hip_bfloat162 p2 = __float22bfloat162_rn(make_float2(v[4], v[5]));
      __hip_bfloat162 p3 = __float22bfloat162_rn(make_float2(v[6], v[7]));
      uint4 o;
      o.x = *(unsigned int*)&p0; o.y = *(unsigned int*)&p1;
      o.z = *(unsigned int*)&p2; o.w = *(unsigned int*)&p3;
      aggb4[(size_t)i * 16 + lr] = o;
    }
  }
}

// ------- fused MFMA GEMM: rst = PReLU(hb@Ws2 + aggb@Wn2 + beff) --------------
// R9 staging (async global_load_lds, pre-swizzled source) + R11 epilogue:
// per-block BN stats AND per-graph pooling (rows gid-sorted; single-graph
// blocks reuse the stat sum ls[]; multi-graph via 4-slot LDS pool + fallback).
__global__ __launch_bounds__(256) void k_gemm_fused(
    const __hip_bfloat16* __restrict__ hb, const __hip_bfloat16* __restrict__ aggb,
    const __hip_bfloat16* __restrict__ Wst2, const __hip_bfloat16* __restrict__ Wnt2,
    const float* __restrict__ beff, const float* __restrict__ pw,
    const int* __restrict__ gid, float* __restrict__ out,
    __hip_bfloat16* __restrict__ hbn, float* __restrict__ partial,
    int l, int store_h, int n) {
  __shared__ short Ah[128 * 128];
  __shared__ short Aa[128 * 128];
  __shared__ float ls[128], lq[128];
  __shared__ float pool[POOLG][128];
  int t = threadIdx.x;
  int row0 = blockIdx.x * 128;
  if (t < 128) { ls[t] = 0.f; lq[t] = 0.f; }
  for (int idx = t; idx < POOLG * 128; idx += 256) pool[idx >> 7][idx & 127] = 0.f;
  int w = t >> 6, lane = t & 63;

  // ---- async stage: 8 rounds x (Ah, Aa), 16B/lane, LDS dest linear ----
#pragma unroll
  for (int rd = 0; rd < 8; ++rd) {
    int Gq = rd * 256 + w * 64 + lane;       // granule id 0..2047 (16B each)
    int r = Gq >> 4;                          // local row 0..127
    int gq = (Gq & 15) ^ (r & 7);             // pre-swizzled source granule
    int grow = row0 + r;
    grow = grow < n ? grow : n - 1;           // clamp: garbage rows never used
    const __hip_bfloat16* gs = hb   + (size_t)grow * 128 + gq * 8;
    const __hip_bfloat16* ga = aggb + (size_t)grow * 128 + gq * 8;
    __builtin_amdgcn_global_load_lds((gconst_t*)gs,
        (ldsv_t*)&Ah[(rd * 256 + w * 64) * 8], 16, 0, 0);
    __builtin_amdgcn_global_load_lds((gconst_t*)ga,
        (ldsv_t*)&Aa[(rd * 256 + w * 64) * 8], 16, 0, 0);
  }
  asm volatile("s_waitcnt vmcnt(0)" ::: "memory");
  __syncthreads();

  // ---- MFMA: A from LDS (swizzled read), B from global (L2-hot) ----
  int lr16 = lane & 15, hi = lane >> 4;
  f32x4 acc[2][8];
#pragma unroll
  for (int fm = 0; fm < 2; ++fm)
#pragma unroll
    for (int fn = 0; fn < 8; ++fn) acc[fm][fn] = (f32x4){0.f, 0.f, 0.f, 0.f};

  const short* As[2] = {Ah, Aa};
  const __hip_bfloat16* Bt[2] = {Wst2, Wnt2};
#pragma unroll
  for (int s = 0; s < 2; ++s) {
    const short* A = As[s];
    const __hip_bfloat16* B = Bt[s];
#pragma unroll
    for (int ks = 0; ks < 4; ++ks) {
      bf16x8 af[2], bfr[8];
#pragma unroll
      for (int fm = 0; fm < 2; ++fm) {
        int rl = w * 32 + fm * 16 + lr16;
        int gq = (ks * 4 + hi) ^ (lr16 & 7);
        af[fm] = *(const bf16x8*)&A[rl * 128 + gq * 8];
      }
#pragma unroll
      for (int fn = 0; fn < 8; ++fn)
        bfr[fn] = *(const bf16x8*)(B + (size_t)(fn * 16 + lr16) * 128 + ks * 32 + hi * 8);
#pragma unroll
      for (int fm = 0; fm < 2; ++fm)
#pragma unroll
        for (int fn = 0; fn < 8; ++fn)
          acc[fm][fn] = __builtin_amdgcn_mfma_f32_16x16x32_bf16(af[fm], bfr[fn], acc[fm][fn], 0, 0, 0);
    }
  }

  // ---- graph span of this block (rows are gid-sorted) ----
  int rowLast = min(row0 + 127, n - 1);
  int g0 = gid[min(row0, n - 1)];
  int g1 = gid[rowLast];
  bool uni = (g0 == g1);

  // ---- epilogue: beff + PReLU + bf16 store + stats + pooling ----
  int rb = hi * 4;             // C/D: col = lane&15, row = 4*(lane>>4)+reg  [m89]
  float sacc[8], qacc[8];
#pragma unroll
  for (int fn = 0; fn < 8; ++fn) { sacc[fn] = 0.f; qacc[fn] = 0.f; }
#pragma unroll
  for (int fm = 0; fm < 2; ++fm) {
    int rbase = row0 + w * 32 + fm * 16 + rb;
    int gv[4];
#pragma unroll
    for (int r = 0; r < 4; ++r) {
      int grow = rbase + r;
      gv[r] = (grow < n) ? gid[grow] : -1;
    }
#pragma unroll
    for (int fn = 0; fn < 8; ++fn) {
      int col = fn * 16 + lr16;
      float bb = beff[col], pp = pw[col];
#pragma unroll
      for (int r = 0; r < 4; ++r) {
        int grow = rbase + r;
        if (grow < n) {
          float v = acc[fm][fn][r] + bb;
          v = v > 0.f ? v : pp * v;
          if (store_h) hbn[(size_t)grow * 128 + col] = __float2bfloat16(v);
          sacc[fn] += v; qacc[fn] += v * v;
          if (!uni) {
            int rel = gv[r] - g0;
            if (rel < POOLG) atomicAdd(&pool[rel][col], v);
            else atomicAdd(&out[(size_t)gv[r] * 512 + l * 128 + col], v);
          }
        }
      }
    }
  }
#pragma unroll
  for (int fn = 0; fn < 8; ++fn) {
    int col = fn * 16 + lr16;
    atomicAdd(&ls[col], sacc[fn]);
    atomicAdd(&lq[col], qacc[fn]);
  }
  __syncthreads();
  if (t < 128) {
    float* pp2 = partial + (size_t)(blockIdx.x >> 3) * 256;
    atomicAdd(&pp2[t], ls[t]);
    atomicAdd(&pp2[128 + t], lq[t]);
    if (uni) {
      atomicAdd(&out[(size_t)g0 * 512 + l * 128 + t], ls[t]);
    } else {
      int span = g1 - g0;
#pragma unroll
      for (int rel = 0; rel < POOLG; ++rel)
        if (rel <= span) atomicAdd(&out[(size_t)(g0 + rel) * 512 + l * 128 + t], pool[rel][t]);
    }
  }
}

// ------------- reduce partial stats -> BN affine + next-layer eff. bias ------
// beff uses ORIGINAL fp32 weights [k][n] layout -> coalesced loads.
__global__ __launch_bounds__(1024) void k_bnfin(const float* __restrict__ partial, int nb,
                                                const float* __restrict__ gamma,
                                                const float* __restrict__ beta,
                                                float* __restrict__ ss,
                                                const float* __restrict__ bias_next,
                                                const float* __restrict__ Ws_next,
                                                const float* __restrict__ Wn_next,
                                                float* __restrict__ beff_next,
                                                int has_next, int n) {
  __shared__ float red[4][256];
  __shared__ float shv[128];
  __shared__ float bred[8][128];
  int t = threadIdx.x, c = t & 255, part = t >> 8;
  float s = 0.f;
  for (int b = part; b < nb; b += 4) s += partial[(size_t)b * 256 + c];
  red[part][c] = s;
  __syncthreads();
  if (part == 0) red[0][c] = red[0][c] + red[1][c] + red[2][c] + red[3][c];
  __syncthreads();
  if (t < 128) {
    float inv_n = 1.0f / (float)n;
    float mu = red[0][t] * inv_n;
    float var = red[0][128 + t] * inv_n - mu * mu;
    float sc = rsqrtf(var + EPS_BN) * gamma[t];
    float sh = beta[t] - mu * sc;
    ss[t] = sc;
    ss[128 + t] = sh;
    shv[t] = sh;
  }
  __syncthreads();
  if (has_next) {
    int cc = t & 127, kg = t >> 7;       // 8 k-groups x 128 channels
    float acc = 0.f;
#pragma unroll
    for (int k = kg * 16; k < kg * 16 + 16; ++k)
      acc += shv[k] * (Ws_next[k * 128 + cc] + Wn_next[k * 128 + cc]);
    bred[kg][cc] = acc;
    __syncthreads();
    if (t < 128) {
      float r = bias_next[t];
#pragma unroll
      for (int kg2 = 0; kg2 < 8; ++kg2) r += bred[kg2][t];
      beff_next[t] = r;
    }
  }
}

// ------------- finalize: mean + BN affine per layer section ------------------
__global__ __launch_bounds__(256) void k_div(float* __restrict__ out, const int* __restrict__ gcnt,
                                             const float* __restrict__ ssbuf, int m) {
  int i = blockIdx.x * 256 + threadIdx.x;
  if (i < m) {
    int g = i >> 9;
    int lc = i & 511;
    int l = lc >> 7, c = lc & 127;
    const float* ss = ssbuf + (l + 1) * 256;
    int cn = gcnt[g];
    out[i] = (cn > 0) ? (out[i] / (float)cn) * ss[c] + ss[128 + c] : 0.f;
  }
}

extern "C" void kernel_launch(void* const* d_in, const int* in_sizes, int n_in,
                              void* d_out, int out_size, void* d_ws, size_t ws_size,
                              hipStream_t stream) {
  const int*   in_feat = (const int*)d_in[0];
  const int*   src     = (const int*)d_in[1];
  const int*   dst     = (const int*)d_in[2];
  const int*   gid     = (const int*)d_in[3];
  const float* emb     = (const float*)d_in[4];
  const float* Wself   = (const float*)d_in[5];
  const float* Wneigh  = (const float*)d_in[6];
  const float* bvec    = (const float*)d_in[7];
  const float* gamma   = (const float*)d_in[8];
  const float* beta    = (const float*)d_in[9];
  const float* prelu   = (const float*)d_in[10];
  const int N = in_sizes[0];
  const int E = in_sizes[1];
  const int G = out_size / 512;
  float* out = (float*)d_out;
  const int NB = (N + 127) / 128;          // gemm blocks
  const int NP = (NB + 7) / 8;             // stat slots (8 blocks/slot)
  const int NBKT = (N + 511) >> BSH;       // buckets (<=256 for N<=128K)

  char* p = (char*)d_ws;
  size_t off = 0;
  auto take = [&](size_t bytes) { void* r = p + off; off += (bytes + 255) & ~(size_t)255; return r; };
  __hip_bfloat16* hb0   = (__hip_bfloat16*)take((size_t)N * 128 * 2);
  __hip_bfloat16* hb1   = (__hip_bfloat16*)take((size_t)N * 128 * 2);
  __hip_bfloat16* aggb  = (__hip_bfloat16*)take((size_t)N * 128 * 2);
  __hip_bfloat16* Wst   = (__hip_bfloat16*)take((size_t)4 * 128 * 128 * 2);
  __hip_bfloat16* Wnt   = (__hip_bfloat16*)take((size_t)4 * 128 * 128 * 2);
  __hip_bfloat16* Wst2  = (__hip_bfloat16*)take((size_t)128 * 128 * 2);
  __hip_bfloat16* Wnt2  = (__hip_bfloat16*)take((size_t)128 * 128 * 2);
  float* partial        = (float*)take((size_t)NP * 256 * 4);
  float* ssbuf          = (float*)take((size_t)5 * 256 * 4);  // [l][sc|sh], l=0 identity
  float* beff           = (float*)take((size_t)4 * 128 * 4);
  uint2* binned  = (uint2*)take((size_t)E * 8);
  int*   csr_src = (int*)take((size_t)E * 4);
  int*   cnt     = (int*)take((size_t)N * 4);
  int*   rp      = (int*)take((size_t)(N + 1) * 4);
  int*   cursor  = (int*)take((size_t)N * 4);
  float* deg     = (float*)take((size_t)N * 4);
  int*   bs      = (int*)take(512);
  int*   gcnt    = (int*)take((size_t)G * 4);
  int*   gstart  = (int*)take((size_t)G * 4);
  int*   bktcnt  = (int*)take((size_t)NBKT * 4);
  int*   bbase   = (int*)take((size_t)(NBKT + 1) * 4);
  int*   bcur    = (int*)take((size_t)NBKT * 4);
  if (off > ws_size) return;

  hipMemsetAsync(bktcnt, 0, (size_t)NBKT * 4, stream);
  hipMemsetAsync(d_out, 0, (size_t)out_size * 4, stream);

  k_embed<<<(N * 64 + 255) / 256, 256, 0, stream>>>(in_feat, emb, (__hip_bfloat162*)hb0, N);
  k_wconv<<<(4 * 128 * 128 + 255) / 256, 256, 0, stream>>>(Wself, Wst, 4 * 128 * 128);
  k_wconv<<<(4 * 128 * 128 + 255) / 256, 256, 0, stream>>>(Wneigh, Wnt, 4 * 128 * 128);
  k_gcount<<<1, 128, 0, stream>>>(gid, gcnt, gstart, N, G);

  int nbb = (E + BCHUNK - 1) / BCHUNK;
  k_bhist<<<nbb, 256, 0, stream>>>(dst, bktcnt, E, NBKT);
  k_bscan<<<1, 256, 0, stream>>>(bktcnt, bbase, bcur, E, NBKT);
  k_bin<<<nbb, 256, 0, stream>>>(src, dst, bcur, binned, E, NBKT);
  k_cnt<<<NBKT, 256, 0, stream>>>(binned, bbase, cnt, N);
  int nsb = (N + 1023) / 1024;
  k_scan1<<<nsb, 256, 0, stream>>>(cnt, rp, bs, N);
  k_scan2<<<1, 128, 0, stream>>>(bs, nsb);
  k_scan3<<<(N + 255) / 256, 256, 0, stream>>>(rp, bs, cnt, cursor, deg, N, E);
  k_place<<<NBKT, 256, 0, stream>>>(binned, bbase, rp, cursor, csr_src, N);
  k_prep<<<1, 128, 0, stream>>>(bvec, ssbuf, beff);

  __hip_bfloat16* bufs[2] = {hb0, hb1};
  for (int l = 0; l < 4; ++l) {
    __hip_bfloat16* hin  = bufs[l & 1];
    __hip_bfloat16* hout = bufs[(l + 1) & 1];
    k_agg<<<2048, 256, 0, stream>>>((const uint4*)hin, rp, csr_src, deg,
                                    ssbuf + l * 256,
                                    Wst + l * 16384, Wnt + l * 16384, Wst2, Wnt2,
                                    (uint4*)aggb, N);
    hipMemsetAsync(partial, 0, (size_t)NP * 256 * 4, stream);
    k_gemm_fused<<<NB, 256, 0, stream>>>(hin, aggb, Wst2, Wnt2,
                                         beff + l * 128, prelu + l * 128,
                                         gid, out, hout, partial,
                                         l, (l < 3) ? 1 : 0, N);
    k_bnfin<<<1, 1024, 0, stream>>>(partial, NP, gamma + l * 128, beta + l * 128,
                                    ssbuf + (l + 1) * 256,
                                    bvec + ((l + 1) & 3) * 128,
                                    Wself + ((l + 1) & 3) * 16384,
                                    Wneigh + ((l + 1) & 3) * 16384,
                                    beff + ((l + 1) & 3) * 128,
                                    (l < 3) ? 1 : 0, N);
  }
  k_div<<<(out_size + 255) / 256, 256, 0, stream>>>(out, gcnt, ssbuf, out_size);
}

// Round 10
// 684.565 us; speedup vs baseline: 1.9095x; 1.1427x over previous
//
#include <hip/hip_runtime.h>
#include <hip/hip_bf16.h>

// GraphSAGE 4-layer forward.
// R2: bf16 activations; aggregate-then-GEMM; fused MFMA GEMM + partial stats.
// R3: k_agg MLP restructure (16-lane groups x dwordx4, 8 edges/iter).
// R4: BN folded into next layer (sc -> B-tile scale, sh -> effective bias).
// R5: binned CSR build (LDS counting sort, coalesced writes).
// R6-R10: GEMM wall study -- ~72us floor (R9 async global_load_lds best);
//     schedule/occupancy-invariant. k_bnfin's 784-slot scan was ~25us/layer.
// R11: slot-stats (8 blocks/slot) won; pooling-in-GEMM REGRESSED (+40us/layer).
// R12: R9 GEMM epilogue restored (72us config) + slot-stats kept + pooling
//     un-fused into 8-chunks-per-graph k_pool (1024 blocks, L2-hot read).

#define EPS_BN 1e-5f
#define BSH 9                 // 512 nodes per bucket
#define BCHUNK 4096           // edges per k_bin block
#define PCAP 10240            // max edges per bucket for LDS staging (mean 8192)

typedef __attribute__((ext_vector_type(8))) short bf16x8;
typedef __attribute__((ext_vector_type(4))) float f32x4;
typedef __attribute__((address_space(1))) const void gconst_t;
typedef __attribute__((address_space(3))) void ldsv_t;

// ---------------- embedding gather -> bf16 h ---------------------------------
__global__ __launch_bounds__(256) void k_embed(const int* __restrict__ feat,
                                               const float* __restrict__ emb,
                                               __hip_bfloat162* __restrict__ hb2, int n) {
  int idx = blockIdx.x * 256 + threadIdx.x;   // one bf16x2 each
  if (idx < n * 64) {
    int i = idx >> 6, c2 = idx & 63;
    float2 v = ((const float2*)emb)[feat[i] * 64 + c2];
    hb2[idx] = __float22bfloat162_rn(v);
  }
}

// ---------------- W -> bf16, transposed: Wt[l][n][k] = W[l][k][n] ------------
__global__ __launch_bounds__(256) void k_wconv(const float* __restrict__ W,
                                               __hip_bfloat16* __restrict__ Wt, int total) {
  int idx = blockIdx.x * 256 + threadIdx.x;
  if (idx < total) {
    int l = idx >> 14, r = idx & 16383, nn = r >> 7, kk = r & 127;
    Wt[idx] = __float2bfloat16(W[(l << 14) + kk * 128 + nn]);
  }
}

// ---------------- per-graph node offsets via binary search (gid sorted) ------
__global__ void k_gcount(const int* __restrict__ gid, int* __restrict__ gcnt,
                         int* __restrict__ gstart, int n, int G) {
  int g = blockIdx.x * blockDim.x + threadIdx.x;
  if (g >= G) return;
  int lo0 = 0, hi = n;
  while (lo0 < hi) { int mid = (lo0 + hi) >> 1; if (gid[mid] < g) lo0 = mid + 1; else hi = mid; }
  int lo1 = lo0; hi = n;
  while (lo1 < hi) { int mid = (lo1 + hi) >> 1; if (gid[mid] < g + 1) lo1 = mid + 1; else hi = mid; }
  gstart[g] = lo0;
  gcnt[g] = lo1 - lo0;
}

// ---------------- bucket histogram over dst (LDS-staged) ---------------------
__global__ __launch_bounds__(256) void k_bhist(const int* __restrict__ dst,
                                               int* __restrict__ bktcnt, int m, int nbkt) {
  __shared__ int h[256];
  int t = threadIdx.x;
  h[t] = 0;
  __syncthreads();
#pragma unroll
  for (int k = 0; k < 4; ++k) {
    int idx = blockIdx.x * BCHUNK + k * 1024 + t * 4;
    if (idx + 4 <= m) {
      int4 d = *(const int4*)&dst[idx];
      atomicAdd(&h[d.x >> BSH], 1);
      atomicAdd(&h[d.y >> BSH], 1);
      atomicAdd(&h[d.z >> BSH], 1);
      atomicAdd(&h[d.w >> BSH], 1);
    } else {
      for (int e = idx; e < m && e < idx + 4; ++e) atomicAdd(&h[dst[e] >> BSH], 1);
    }
  }
  __syncthreads();
  for (int b = t; b < nbkt; b += 256)
    if (h[b]) atomicAdd(&bktcnt[b], h[b]);
}

// ---------------- scan bucket counts -> base & cursor ------------------------
__global__ void k_bscan(const int* __restrict__ bktcnt, int* __restrict__ bbase,
                        int* __restrict__ bcur, int m, int nbkt) {
  __shared__ int sh[256];
  int t = threadIdx.x;
  int v = (t < nbkt) ? bktcnt[t] : 0;
  sh[t] = v;
  __syncthreads();
  for (int o = 1; o < 256; o <<= 1) {
    int x = (t >= o) ? sh[t - o] : 0;
    __syncthreads();
    sh[t] += x;
    __syncthreads();
  }
  if (t < nbkt) { bbase[t] = sh[t] - v; bcur[t] = sh[t] - v; }
  if (t == 0) bbase[nbkt] = m;
}

// ---------------- bin edges by bucket (LDS counting sort, coalesced out) -----
__global__ __launch_bounds__(256) void k_bin(const int* __restrict__ src, const int* __restrict__ dst,
                                             int* __restrict__ bcur, uint2* __restrict__ binned,
                                             int m, int nbkt) {
  __shared__ uint2 st[BCHUNK];
  __shared__ int bcnt[256], boff[256], bres[256], wcur[256], ss[256];
  int t = threadIdx.x;
  int e0 = blockIdx.x * BCHUNK;
  int cn = min(BCHUNK, m - e0);
  int sv[16], dv[16];
  for (int b = t; b < 256; b += 256) bcnt[b] = 0;
  __syncthreads();
#pragma unroll
  for (int k = 0; k < 16; ++k) {
    int idx = e0 + k * 256 + t;
    if (idx < e0 + cn) {
      sv[k] = src[idx];
      dv[k] = dst[idx];
      atomicAdd(&bcnt[dv[k] >> BSH], 1);
    } else dv[k] = -1;
  }
  __syncthreads();
  int v = (t < nbkt) ? bcnt[t] : 0;
  ss[t] = v;
  __syncthreads();
  for (int o = 1; o < 256; o <<= 1) {
    int x = (t >= o) ? ss[t - o] : 0;
    __syncthreads();
    ss[t] += x;
    __syncthreads();
  }
  if (t < nbkt) {
    int ex = ss[t] - v;
    boff[t] = ex;
    wcur[t] = ex;
    if (v) bres[t] = atomicAdd(&bcur[t], v);
  }
  __syncthreads();
#pragma unroll
  for (int k = 0; k < 16; ++k) {
    if (dv[k] >= 0) {
      int b = dv[k] >> BSH;
      int p = atomicAdd(&wcur[b], 1);
      st[p] = make_uint2((unsigned)sv[k], (unsigned)dv[k]);
    }
  }
  __syncthreads();
  for (int j = t; j < cn; j += 256) {
    uint2 e = st[j];
    int b = (int)(e.y >> BSH);
    binned[(size_t)bres[b] + (j - boff[b])] = e;
  }
}

// ---------------- per-bucket node counts (LDS, coalesced cnt write) ----------
__global__ __launch_bounds__(256) void k_cnt(const uint2* __restrict__ binned,
                                             const int* __restrict__ bbase,
                                             int* __restrict__ cnt, int n) {
  __shared__ int h[512];
  int b = blockIdx.x, t = threadIdx.x;
  int base = b << BSH;
  int nn = min(512, n - base);
  h[t] = 0; h[t + 256] = 0;
  __syncthreads();
  int lo = bbase[b], hi = bbase[b + 1];
  for (int j = lo + t; j < hi; j += 256) atomicAdd(&h[(int)binned[j].y - base], 1);
  __syncthreads();
  if (t < nn) cnt[base + t] = h[t];
  if (t + 256 < nn) cnt[base + t + 256] = h[t + 256];
}

// ---------------- exclusive scan of cnt -> row_ptr (3 kernels) ---------------
__global__ __launch_bounds__(256) void k_scan1(const int* __restrict__ cnt,
                                               int* __restrict__ excl,
                                               int* __restrict__ blk_sums, int n) {
  __shared__ int sh[256];
  int t = threadIdx.x;
  int base = blockIdx.x * 1024 + t * 4;
  int4 v = {0, 0, 0, 0};
  if (base < n) v = *(const int4*)&cnt[base];
  int s = v.x + v.y + v.z + v.w;
  sh[t] = s;
  __syncthreads();
  for (int off = 1; off < 256; off <<= 1) {
    int x = (t >= off) ? sh[t - off] : 0;
    __syncthreads();
    sh[t] += x;
    __syncthreads();
  }
  int ex = sh[t] - s;
  if (t == 255) blk_sums[blockIdx.x] = sh[255];
  if (base < n) {
    excl[base]     = ex;
    excl[base + 1] = ex + v.x;
    excl[base + 2] = ex + v.x + v.y;
    excl[base + 3] = ex + v.x + v.y + v.z;
  }
}

__global__ void k_scan2(int* __restrict__ bs, int nb) {
  __shared__ int sh[128];
  int t = threadIdx.x;
  int v = (t < nb) ? bs[t] : 0;
  sh[t] = v;
  __syncthreads();
  for (int off = 1; off < 128; off <<= 1) {
    int x = (t >= off) ? sh[t - off] : 0;
    __syncthreads();
    sh[t] += x;
    __syncthreads();
  }
  if (t < nb) bs[t] = sh[t] - v;
}

__global__ __launch_bounds__(256) void k_scan3(int* __restrict__ rp, const int* __restrict__ bs,
                                               const int* __restrict__ cnt, int* __restrict__ cursor,
                                               float* __restrict__ deg, int n, int ne) {
  int i = blockIdx.x * 256 + threadIdx.x;
  if (i < n) {
    int r = rp[i] + bs[i >> 10];
    rp[i] = r;
    cursor[i] = r;
    int c = cnt[i];
    deg[i] = (float)(c > 0 ? c : 1);
  }
  if (i == 0) rp[n] = ne;
}

// ---------------- place edges into CSR (per-bucket LDS sort, coalesced) ------
__global__ __launch_bounds__(256) void k_place(const uint2* __restrict__ binned,
                                               const int* __restrict__ bbase,
                                               const int* __restrict__ rp,
                                               int* __restrict__ cursor,
                                               int* __restrict__ csr_src, int n) {
  int b = blockIdx.x, t = threadIdx.x;
  int base = b << BSH;
  int lo = bbase[b], hi = bbase[b + 1], m = hi - lo;
  if (m <= 0) return;
  if (m > PCAP) {                          // fallback: global-atomic scatter
    for (int j = lo + t; j < hi; j += 256) {
      uint2 e = binned[j];
      int p = atomicAdd(&cursor[(int)e.y], 1);
      csr_src[p] = (int)e.x;
    }
    return;
  }
  __shared__ int h[512], loff[512], wc[512], ss[256];
  __shared__ int stage[PCAP];
  h[t] = 0; h[t + 256] = 0;
  __syncthreads();
  for (int j = lo + t; j < hi; j += 256) atomicAdd(&h[(int)binned[j].y - base], 1);
  __syncthreads();
  int a0 = h[2 * t], a1 = h[2 * t + 1];
  int s = a0 + a1;
  ss[t] = s;
  __syncthreads();
  for (int o = 1; o < 256; o <<= 1) {
    int x = (t >= o) ? ss[t - o] : 0;
    __syncthreads();
    ss[t] += x;
    __syncthreads();
  }
  int ex = ss[t] - s;
  loff[2 * t] = ex; loff[2 * t + 1] = ex + a0;
  wc[2 * t] = ex;   wc[2 * t + 1] = ex + a0;
  __syncthreads();
  for (int j = lo + t; j < hi; j += 256) {
    uint2 e = binned[j];
    int p = atomicAdd(&wc[(int)e.y - base], 1);
    stage[p] = (int)e.x;
  }
  __syncthreads();
  int cb = rp[base];
  for (int j = t; j < m; j += 256) csr_src[cb + j] = stage[j];
}

// ---------------- init: identity BN affine + layer-0 effective bias ----------
__global__ void k_prep(const float* __restrict__ b0, float* __restrict__ ss0,
                       float* __restrict__ beff0) {
  int t = threadIdx.x;
  ss0[t] = 1.f;
  ss0[128 + t] = 0.f;
  beff0[t] = b0[t];
}

// ---------------- mean-aggregate bf16 h rows -> bf16 agg + W pre-scale -------
__device__ __forceinline__ void acc8(float* a, uint4 v) {
  float2 f;
  f = __bfloat1622float2(*(const __hip_bfloat162*)&v.x); a[0] += f.x; a[1] += f.y;
  f = __bfloat1622float2(*(const __hip_bfloat162*)&v.y); a[2] += f.x; a[3] += f.y;
  f = __bfloat1622float2(*(const __hip_bfloat162*)&v.z); a[4] += f.x; a[5] += f.y;
  f = __bfloat1622float2(*(const __hip_bfloat162*)&v.w); a[6] += f.x; a[7] += f.y;
}

__global__ __launch_bounds__(256) void k_agg(const uint4* __restrict__ hb4,
                                             const int* __restrict__ rp, const int* __restrict__ csr_src,
                                             const float* __restrict__ deg,
                                             const float* __restrict__ ssl,   // prev-layer [sc|sh]
                                             const __hip_bfloat16* __restrict__ Wst,
                                             const __hip_bfloat16* __restrict__ Wnt,
                                             __hip_bfloat16* __restrict__ Wst2,
                                             __hip_bfloat16* __restrict__ Wnt2,
                                             uint4* __restrict__ aggb4, int n) {
  int lane = threadIdx.x & 63, wid = threadIdx.x >> 6;
  int g = lane >> 4, lr = lane & 15;
  // first 16 blocks also pre-scale this layer's W by sc[k]: 4096 uint4 chunks
  if (blockIdx.x < 16) {
    int id = blockIdx.x * 256 + threadIdx.x;     // 0..4095
    int half = id >> 11;                          // 0: Ws, 1: Wn
    int ch = id & 2047;                           // uint4 chunk within 16384 el
    const uint4* Wsrc = (const uint4*)(half ? Wnt : Wst);
    uint4* Wdst = (uint4*)(half ? Wnt2 : Wst2);
    uint4 v = Wsrc[ch];
    int k0 = (ch * 8) & 127;
    __hip_bfloat162* pv = (__hip_bfloat162*)&v;
#pragma unroll
    for (int j = 0; j < 4; ++j) {
      float2 f = __bfloat1622float2(pv[j]);
      f.x *= ssl[k0 + 2 * j]; f.y *= ssl[k0 + 2 * j + 1];
      pv[j] = __float22bfloat162_rn(f);
    }
    Wdst[ch] = v;
  }
  for (int i = blockIdx.x * 4 + wid; i < n; i += gridDim.x * 4) {
    int beg = rp[i], end = rp[i + 1];
    float a[8];
#pragma unroll
    for (int c = 0; c < 8; ++c) a[c] = 0.f;
    int e = beg;
    for (; e + 8 <= end; e += 8) {        // 8 edges per wave-iteration
      int s0 = csr_src[e + g];
      int s1 = csr_src[e + 4 + g];
      uint4 v0 = hb4[(size_t)s0 * 16 + lr];
      uint4 v1 = hb4[(size_t)s1 * 16 + lr];
      acc8(a, v0);
      acc8(a, v1);
    }
    for (; e + g < end; e += 4) {         // predicated 4-edge tail
      int s = csr_src[e + g];
      uint4 v = hb4[(size_t)s * 16 + lr];
      acc8(a, v);
    }
#pragma unroll
    for (int c = 0; c < 8; ++c) {         // combine the 4 groups
      a[c] += __shfl_xor(a[c], 16, 64);
      a[c] += __shfl_xor(a[c], 32, 64);
    }
    if (g == 0) {
      float v[8];
      if (beg == end) {                   // zero-degree: cancel folded affine
#pragma unroll
        for (int c = 0; c < 8; ++c) {
          float sc = ssl[lr * 8 + c], sh = ssl[128 + lr * 8 + c];
          v[c] = (sc != 0.f) ? (-sh / sc) : 0.f;
        }
      } else {
        float invd = 1.0f / deg[i];
#pragma unroll
        for (int c = 0; c < 8; ++c) v[c] = a[c] * invd;
      }
      __hip_bfloat162 p0 = __float22bfloat162_rn(make_float2(v[0], v[1]));
      __hip_bfloat162 p1 = __float22bfloat162_rn(make_float2(v[2], v[3]));
      __hip_bfloat162 p2 = __float22bfloat162_rn(make_float2(v[4], v[5]));
      __hip_bfloat162 p3 = __float22bfloat162_rn(make_float2(v[6], v[7]));
      uint4 o;
      o.x = *(unsigned int*)&p0; o.y = *(unsigned int*)&p1;
      o.z = *(unsigned int*)&p2; o.w = *(unsigned int*)&p3;
      aggb4[(size_t)i * 16 + lr] = o;
    }
  }
}

// ------- fused MFMA GEMM: rst = PReLU(hb@Ws2 + aggb@Wn2 + beff) --------------
// R9 config verbatim (72us): async global_load_lds staging, pre-swizzled
// source, swizzled ds_read; only change: stats atomicAdd into shared slot.
__global__ __launch_bounds__(256) void k_gemm_fused(
    const __hip_bfloat16* __restrict__ hb, const __hip_bfloat16* __restrict__ aggb,
    const __hip_bfloat16* __restrict__ Wst2, const __hip_bfloat16* __restrict__ Wnt2,
    const float* __restrict__ beff, const float* __restrict__ pw,
    __hip_bfloat16* __restrict__ hbn, float* __restrict__ partial, int n) {
  __shared__ short Ah[128 * 128];
  __shared__ short Aa[128 * 128];
  __shared__ float ls[128], lq[128];
  int t = threadIdx.x;
  int row0 = blockIdx.x * 128;
  if (t < 128) { ls[t] = 0.f; lq[t] = 0.f; }
  int w = t >> 6, lane = t & 63;

  // ---- async stage: 8 rounds x (Ah, Aa), 16B/lane, LDS dest linear ----
#pragma unroll
  for (int rd = 0; rd < 8; ++rd) {
    int Gq = rd * 256 + w * 64 + lane;       // granule id 0..2047 (16B each)
    int r = Gq >> 4;                          // local row 0..127
    int gq = (Gq & 15) ^ (r & 7);             // pre-swizzled source granule
    int grow = row0 + r;
    grow = grow < n ? grow : n - 1;           // clamp: garbage rows never used
    const __hip_bfloat16* gs = hb   + (size_t)grow * 128 + gq * 8;
    const __hip_bfloat16* ga = aggb + (size_t)grow * 128 + gq * 8;
    __builtin_amdgcn_global_load_lds((gconst_t*)gs,
        (ldsv_t*)&Ah[(rd * 256 + w * 64) * 8], 16, 0, 0);
    __builtin_amdgcn_global_load_lds((gconst_t*)ga,
        (ldsv_t*)&Aa[(rd * 256 + w * 64) * 8], 16, 0, 0);
  }
  asm volatile("s_waitcnt vmcnt(0)" ::: "memory");
  __syncthreads();

  // ---- MFMA: A from LDS (swizzled read), B from global (L2-hot) ----
  int lr16 = lane & 15, hi = lane >> 4;
  f32x4 acc[2][8];
#pragma unroll
  for (int fm = 0; fm < 2; ++fm)
#pragma unroll
    for (int fn = 0; fn < 8; ++fn) acc[fm][fn] = (f32x4){0.f, 0.f, 0.f, 0.f};

  const short* As[2] = {Ah, Aa};
  const __hip_bfloat16* Bt[2] = {Wst2, Wnt2};
#pragma unroll
  for (int s = 0; s < 2; ++s) {
    const short* A = As[s];
    const __hip_bfloat16* B = Bt[s];
#pragma unroll
    for (int ks = 0; ks < 4; ++ks) {
      bf16x8 af[2], bfr[8];
#pragma unroll
      for (int fm = 0; fm < 2; ++fm) {
        int rl = w * 32 + fm * 16 + lr16;
        int gq = (ks * 4 + hi) ^ (lr16 & 7);
        af[fm] = *(const bf16x8*)&A[rl * 128 + gq * 8];
      }
#pragma unroll
      for (int fn = 0; fn < 8; ++fn)
        bfr[fn] = *(const bf16x8*)(B + (size_t)(fn * 16 + lr16) * 128 + ks * 32 + hi * 8);
#pragma unroll
      for (int fm = 0; fm < 2; ++fm)
#pragma unroll
        for (int fn = 0; fn < 8; ++fn)
          acc[fm][fn] = __builtin_amdgcn_mfma_f32_16x16x32_bf16(af[fm], bfr[fn], acc[fm][fn], 0, 0, 0);
    }
  }

  // ---- epilogue: beff + PReLU + bf16 store + per-block stats ----
  int rb = hi * 4;             // C/D: col = lane&15, row = 4*(lane>>4)+reg  [m89]
  float sacc[8], qacc[8];
#pragma unroll
  for (int fn = 0; fn < 8; ++fn) { sacc[fn] = 0.f; qacc[fn] = 0.f; }
#pragma unroll
  for (int fm = 0; fm < 2; ++fm) {
    int rbase = row0 + w * 32 + fm * 16 + rb;
#pragma unroll
    for (int fn = 0; fn < 8; ++fn) {
      int col = fn * 16 + lr16;
      float bb = beff[col], pp = pw[col];
#pragma unroll
      for (int r = 0; r < 4; ++r) {
        int grow = rbase + r;
        if (grow < n) {
          float v = acc[fm][fn][r] + bb;
          v = v > 0.f ? v : pp * v;
          hbn[(size_t)grow * 128 + col] = __float2bfloat16(v);
          sacc[fn] += v; qacc[fn] += v * v;
        }
      }
    }
  }
#pragma unroll
  for (int fn = 0; fn < 8; ++fn) {
    int col = fn * 16 + lr16;
    atomicAdd(&ls[col], sacc[fn]);
    atomicAdd(&lq[col], qacc[fn]);
  }
  __syncthreads();
  if (t < 128) {
    float* pp2 = partial + (size_t)(blockIdx.x >> 3) * 256;
    atomicAdd(&pp2[t], ls[t]);
    atomicAdd(&pp2[128 + t], lq[t]);
  }
}

// ------------- reduce partial stats -> BN affine + next-layer eff. bias ------
// beff uses ORIGINAL fp32 weights [k][n] layout -> coalesced loads.
__global__ __launch_bounds__(1024) void k_bnfin(const float* __restrict__ partial, int nb,
                                                const float* __restrict__ gamma,
                                                const float* __restrict__ beta,
                                                float* __restrict__ ss,
                                                const float* __restrict__ bias_next,
                                                const float* __restrict__ Ws_next,
                                                const float* __restrict__ Wn_next,
                                                float* __restrict__ beff_next,
                                                int has_next, int n) {
  __shared__ float red[4][256];
  __shared__ float shv[128];
  __shared__ float bred[8][128];
  int t = threadIdx.x, c = t & 255, part = t >> 8;
  float s = 0.f;
  for (int b = part; b < nb; b += 4) s += partial[(size_t)b * 256 + c];
  red[part][c] = s;
  __syncthreads();
  if (part == 0) red[0][c] = red[0][c] + red[1][c] + red[2][c] + red[3][c];
  __syncthreads();
  if (t < 128) {
    float inv_n = 1.0f / (float)n;
    float mu = red[0][t] * inv_n;
    float var = red[0][128 + t] * inv_n - mu * mu;
    float sc = rsqrtf(var + EPS_BN) * gamma[t];
    float sh = beta[t] - mu * sc;
    ss[t] = sc;
    ss[128 + t] = sh;
    shv[t] = sh;
  }
  __syncthreads();
  if (has_next) {
    int cc = t & 127, kg = t >> 7;       // 8 k-groups x 128 channels
    float acc = 0.f;
#pragma unroll
    for (int k = kg * 16; k < kg * 16 + 16; ++k)
      acc += shv[k] * (Ws_next[k * 128 + cc] + Wn_next[k * 128 + cc]);
    bred[kg][cc] = acc;
    __syncthreads();
    if (t < 128) {
      float r = bias_next[t];
#pragma unroll
      for (int kg2 = 0; kg2 < 8; ++kg2) r += bred[kg2][t];
      beff_next[t] = r;
    }
  }
}

// ------------- per-graph pool of raw rst (bf16): 8 chunks per graph ----------
__global__ __launch_bounds__(256) void k_pool(const uint4* __restrict__ hb4,
                                              const int* __restrict__ gstart,
                                              const int* __restrict__ gcnt,
                                              float* __restrict__ out, int l) {
  __shared__ float red[4][128];
  int g = blockIdx.x >> 3, c = blockIdx.x & 7;
  int len = gcnt[g];
  int i0 = gstart[g] + ((len * c) >> 3);
  int i1 = gstart[g] + ((len * (c + 1)) >> 3);
  if (i0 >= i1) return;
  int t = threadIdx.x, w = t >> 6, lane = t & 63;
  int gi = lane >> 4, lr = lane & 15;
  float a[8];
#pragma unroll
  for (int cc = 0; cc < 8; ++cc) a[cc] = 0.f;
#pragma unroll 2
  for (int r = i0 + w * 4 + gi; r < i1; r += 16) {   // 16 rows in flight
    uint4 v = hb4[(size_t)r * 16 + lr];
    acc8(a, v);
  }
#pragma unroll
  for (int cc = 0; cc < 8; ++cc) {                   // combine 4 groups in wave
    a[cc] += __shfl_xor(a[cc], 16, 64);
    a[cc] += __shfl_xor(a[cc], 32, 64);
  }
  if (gi == 0) {
#pragma unroll
    for (int cc = 0; cc < 8; ++cc) red[w][lr * 8 + cc] = a[cc];
  }
  __syncthreads();
  if (t < 128)
    atomicAdd(&out[(size_t)g * 512 + l * 128 + t],
              red[0][t] + red[1][t] + red[2][t] + red[3][t]);
}

// ------------- finalize: mean + BN affine per layer section ------------------
__global__ __launch_bounds__(256) void k_div(float* __restrict__ out, const int* __restrict__ gcnt,
                                             const float* __restrict__ ssbuf, int m) {
  int i = blockIdx.x * 256 + threadIdx.x;
  if (i < m) {
    int g = i >> 9;
    int lc = i & 511;
    int l = lc >> 7, c = lc & 127;
    const float* ss = ssbuf + (l + 1) * 256;
    int cn = gcnt[g];
    out[i] = (cn > 0) ? (out[i] / (float)cn) * ss[c] + ss[128 + c] : 0.f;
  }
}

extern "C" void kernel_launch(void* const* d_in, const int* in_sizes, int n_in,
                              void* d_out, int out_size, void* d_ws, size_t ws_size,
                              hipStream_t stream) {
  const int*   in_feat = (const int*)d_in[0];
  const int*   src     = (const int*)d_in[1];
  const int*   dst     = (const int*)d_in[2];
  const int*   gid     = (const int*)d_in[3];
  const float* emb     = (const float*)d_in[4];
  const float* Wself   = (const float*)d_in[5];
  const float* Wneigh  = (const float*)d_in[6];
  const float* bvec    = (const float*)d_in[7];
  const float* gamma   = (const float*)d_in[8];
  const float* beta    = (const float*)d_in[9];
  const float* prelu   = (const float*)d_in[10];
  const int N = in_sizes[0];
  const int E = in_sizes[1];
  const int G = out_size / 512;
  float* out = (float*)d_out;
  const int NB = (N + 127) / 128;          // gemm blocks
  const int NP = (NB + 7) / 8;             // stat slots (8 blocks/slot)
  const int NBKT = (N + 511) >> BSH;       // buckets (<=256 for N<=128K)

  char* p = (char*)d_ws;
  size_t off = 0;
  auto take = [&](size_t bytes) { void* r = p + off; off += (bytes + 255) & ~(size_t)255; return r; };
  __hip_bfloat16* hb0   = (__hip_bfloat16*)take((size_t)N * 128 * 2);
  __hip_bfloat16* hb1   = (__hip_bfloat16*)take((size_t)N * 128 * 2);
  __hip_bfloat16* aggb  = (__hip_bfloat16*)take((size_t)N * 128 * 2);
  __hip_bfloat16* Wst   = (__hip_bfloat16*)take((size_t)4 * 128 * 128 * 2);
  __hip_bfloat16* Wnt   = (__hip_bfloat16*)take((size_t)4 * 128 * 128 * 2);
  __hip_bfloat16* Wst2  = (__hip_bfloat16*)take((size_t)128 * 128 * 2);
  __hip_bfloat16* Wnt2  = (__hip_bfloat16*)take((size_t)128 * 128 * 2);
  float* partial        = (float*)take((size_t)NP * 256 * 4);
  float* ssbuf          = (float*)take((size_t)5 * 256 * 4);  // [l][sc|sh], l=0 identity
  float* beff           = (float*)take((size_t)4 * 128 * 4);
  uint2* binned  = (uint2*)take((size_t)E * 8);
  int*   csr_src = (int*)take((size_t)E * 4);
  int*   cnt     = (int*)take((size_t)N * 4);
  int*   rp      = (int*)take((size_t)(N + 1) * 4);
  int*   cursor  = (int*)take((size_t)N * 4);
  float* deg     = (float*)take((size_t)N * 4);
  int*   bs      = (int*)take(512);
  int*   gcnt    = (int*)take((size_t)G * 4);
  int*   gstart  = (int*)take((size_t)G * 4);
  int*   bktcnt  = (int*)take((size_t)NBKT * 4);
  int*   bbase   = (int*)take((size_t)(NBKT + 1) * 4);
  int*   bcur    = (int*)take((size_t)NBKT * 4);
  if (off > ws_size) return;

  hipMemsetAsync(bktcnt, 0, (size_t)NBKT * 4, stream);
  hipMemsetAsync(d_out, 0, (size_t)out_size * 4, stream);

  k_embed<<<(N * 64 + 255) / 256, 256, 0, stream>>>(in_feat, emb, (__hip_bfloat162*)hb0, N);
  k_wconv<<<(4 * 128 * 128 + 255) / 256, 256, 0, stream>>>(Wself, Wst, 4 * 128 * 128);
  k_wconv<<<(4 * 128 * 128 + 255) / 256, 256, 0, stream>>>(Wneigh, Wnt, 4 * 128 * 128);
  k_gcount<<<1, 128, 0, stream>>>(gid, gcnt, gstart, N, G);

  int nbb = (E + BCHUNK - 1) / BCHUNK;
  k_bhist<<<nbb, 256, 0, stream>>>(dst, bktcnt, E, NBKT);
  k_bscan<<<1, 256, 0, stream>>>(bktcnt, bbase, bcur, E, NBKT);
  k_bin<<<nbb, 256, 0, stream>>>(src, dst, bcur, binned, E, NBKT);
  k_cnt<<<NBKT, 256, 0, stream>>>(binned, bbase, cnt, N);
  int nsb = (N + 1023) / 1024;
  k_scan1<<<nsb, 256, 0, stream>>>(cnt, rp, bs, N);
  k_scan2<<<1, 128, 0, stream>>>(bs, nsb);
  k_scan3<<<(N + 255) / 256, 256, 0, stream>>>(rp, bs, cnt, cursor, deg, N, E);
  k_place<<<NBKT, 256, 0, stream>>>(binned, bbase, rp, cursor, csr_src, N);
  k_prep<<<1, 128, 0, stream>>>(bvec, ssbuf, beff);

  __hip_bfloat16* bufs[2] = {hb0, hb1};
  for (int l = 0; l < 4; ++l) {
    __hip_bfloat16* hin  = bufs[l & 1];
    __hip_bfloat16* hout = bufs[(l + 1) & 1];
    k_agg<<<2048, 256, 0, stream>>>((const uint4*)hin, rp, csr_src, deg,
                                    ssbuf + l * 256,
                                    Wst + l * 16384, Wnt + l * 16384, Wst2, Wnt2,
                                    (uint4*)aggb, N);
    hipMemsetAsync(partial, 0, (size_t)NP * 256 * 4, stream);
    k_gemm_fused<<<NB, 256, 0, stream>>>(hin, aggb, Wst2, Wnt2,
                                         beff + l * 128, prelu + l * 128,
                                         hout, partial, N);
    k_bnfin<<<1, 1024, 0, stream>>>(partial, NP, gamma + l * 128, beta + l * 128,
                                    ssbuf + (l + 1) * 256,
                                    bvec + ((l + 1) & 3) * 128,
                                    Wself + ((l + 1) & 3) * 16384,
                                    Wneigh + ((l + 1) & 3) * 16384,
                                    beff + ((l + 1) & 3) * 128,
                                    (l < 3) ? 1 : 0, N);
    k_pool<<<G * 8, 256, 0, stream>>>((const uint4*)hout, gstart, gcnt, out, l);
  }
  k_div<<<(out_size + 255) / 256, 256, 0, stream>>>(out, gcnt, ssbuf, out_size);
}